// Round 9
// baseline (351.266 us; speedup 1.0000x reference)
//
#include <hip/hip_runtime.h>
#include <hip/hip_bf16.h>

#define NN   207
#define BB   8
#define TT   12
#define EE   64
#define FFD  256
#define NGH  8
#define GALPHA 0.2f
#define GNEG  -9e15f

// ---- Kernel B LDS layout (f32 units) ----
#define SRD   68      // f32 row stride (bank-safe, 16B-aligned)
#define SRD16 72      // bf16 row stride (u16 units)
#define FSRD  264     // FF f32 row stride
#define L_QQ  0       // [12][68]
#define L_X1  816     // [12][68]
#define L_QB  1632    // bf16 [12][72] (u16@2*L_QB)
#define L_KB  2064
#define L_VB  2496
#define L_SC  2928    // 4 heads * 144
#define L_CTX 3504    // [12][68] -> ends 4320
#define L_FF  1632    // alias over QB..CTX (dead there), [12][264] -> ends 4800
#define L_TOTB 4800   // 19200 B

__device__ __forceinline__ float lo_f(unsigned u) { return __uint_as_float(u << 16); }
__device__ __forceinline__ float hi_f(unsigned u) { return __uint_as_float(u & 0xffff0000u); }
__device__ __forceinline__ float b16f(unsigned short s) { return __uint_as_float(((unsigned)s) << 16); }
__device__ __forceinline__ unsigned pk2(float a, float b) {
  unsigned la = (unsigned)__bfloat16_as_ushort(__float2bfloat16(a));
  unsigned lb = (unsigned)__bfloat16_as_ushort(__float2bfloat16(b));
  return la | (lb << 16);
}
__device__ __forceinline__ unsigned short bf16u(float a) {
  return __bfloat16_as_ushort(__float2bfloat16(a));
}
__device__ __forceinline__ float tanh_fast(float x) {
  // tanh(x) = 1 - 2/(e^{2x}+1); v_rcp ~1ulp, well within tolerance
  return 1.f - 2.f * __builtin_amdgcn_rcpf(__expf(2.f * x) + 1.f);
}

// ---- DPP wave reduction: row_ror 1,2,4,8 (in-row sums) + readlane combine ----
__device__ __forceinline__ float row16_sum(float v) {
  v += __int_as_float(__builtin_amdgcn_update_dpp(0, __float_as_int(v), 0x121, 0xf, 0xf, false));
  v += __int_as_float(__builtin_amdgcn_update_dpp(0, __float_as_int(v), 0x122, 0xf, 0xf, false));
  v += __int_as_float(__builtin_amdgcn_update_dpp(0, __float_as_int(v), 0x124, 0xf, 0xf, false));
  v += __int_as_float(__builtin_amdgcn_update_dpp(0, __float_as_int(v), 0x128, 0xf, 0xf, false));
  return v;
}
__device__ __forceinline__ float wave_sum(float v) {
  const float r = row16_sum(v);
  const float a = __int_as_float(__builtin_amdgcn_readlane(__float_as_int(r), 0));
  const float b = __int_as_float(__builtin_amdgcn_readlane(__float_as_int(r), 16));
  const float c = __int_as_float(__builtin_amdgcn_readlane(__float_as_int(r), 32));
  const float d = __int_as_float(__builtin_amdgcn_readlane(__float_as_int(r), 48));
  return (a + b) + (c + d);
}
#define UNPK8(U, f) { (f)[0]=lo_f((U).x); (f)[1]=hi_f((U).x); (f)[2]=lo_f((U).y); (f)[3]=hi_f((U).y); \
                      (f)[4]=lo_f((U).z); (f)[5]=hi_f((U).z); (f)[6]=lo_f((U).w); (f)[7]=hi_f((U).w); }

// ===========================================================================
// Workspace (from d_ws): wbf f32[98304] (393KB), then out0 bf16[8*207*768].
// Total 2.94 MB < 5.09 MB proven watermark.
// ===========================================================================

// ===========================================================================
// Prep: f32 transposed+kb-tiled weights.
// (f32 idx): QT/KT/VT/OT: which*8192 + l*4096 + kb*512 + c*8 + j  (k=8kb+j)
//   W1T: 32768 + l*16384 + kb*2048 + f*8 + j      (kb 0..7)
//   W2T: 65536 + l*16384 + kb*512  + e*8 + j      (kb 0..31)
// ===========================================================================
__global__ __launch_bounds__(256) void prep_weights(
    const float* __restrict__ Wq, const float* __restrict__ Wk,
    const float* __restrict__ Wv, const float* __restrict__ Wo,
    const float* __restrict__ ff_w1, const float* __restrict__ ff_w2,
    float* __restrict__ wb)
{
  const int idx = blockIdx.x * 256 + threadIdx.x;   // < 98304
  float v;
  if (idx < 32768) {
    const int which = idx >> 13;
    const int r = idx & 8191;
    const int l = r >> 12, q = r & 4095;
    const int kb = q >> 9, c = (q >> 3) & 63, j = q & 7;
    const float* W = (which == 0) ? Wq : (which == 1) ? Wk : (which == 2) ? Wv : Wo;
    v = W[l*4096 + (8*kb + j)*64 + c];
  } else if (idx < 65536) {
    const int r = idx - 32768;
    const int l = r >> 14, q = r & 16383;
    const int kb = q >> 11, f = (q >> 3) & 255, j = q & 7;
    v = ff_w1[l*16384 + (8*kb + j)*256 + f];
  } else {
    const int r = idx - 65536;
    const int l = r >> 14, q = r & 16383;
    const int kb = q >> 9, e = (q >> 3) & 63, j = q & 7;
    v = ff_w2[l*16384 + (8*kb + j)*64 + e];
  }
  wb[idx] = v;
}

// ===========================================================================
// Kernel A: GAT (8 heads) + conv1. One block per (b, n). Writes out0 bf16.
// Reductions: DPP row-sums + readlane (no LDS-pipe shuffles, no max-sub).
// ===========================================================================
#define A_GW 2484   // u32 xs_pk[12][207] then 96 floats of GAT params

__global__ __launch_bounds__(256) void gat_conv1_kernel(
    const float* __restrict__ x,        const int* __restrict__ adj,
    const float* __restrict__ gat_W2,   const float* __restrict__ gat_a,
    const float* __restrict__ gat_b,    const float* __restrict__ conv1_w,
    const float* __restrict__ conv1_b,  unsigned short* __restrict__ out0)
{
  __shared__ float lds[A_GW + 96];
  unsigned* au = (unsigned*)lds;

  const int bn   = blockIdx.x;
  const int b    = bn / NN;
  const int i    = bn % NN;
  const int tid  = threadIdx.x;
  const int lane = tid & 63;
  const int wid  = tid >> 6;

  const float* xb = x + b * 2 * NN * TT;
  for (int idx = tid; idx < NN * TT; idx += 256) {
    const int n = idx / TT, t = idx % TT;
    au[t * NN + n] = pk2(xb[idx], xb[NN * TT + idx]);
  }
  if (tid < 64) lds[A_GW + tid] = gat_W2[tid];
  if (tid < 16) { lds[A_GW + 64 + tid] = gat_a[tid]; lds[A_GW + 80 + tid] = gat_b[tid]; }
  __syncthreads();

  int   row0[4], row1[4];
  float aokf[4];
  {
    const int NSQ = NN * NN;
#pragma unroll
    for (int q = 0; q < 4; ++q) {
      const int j = lane + 64 * q;
      const int jj = (j < NN) ? j : 0;
      const int r0 = 2 * (i * NN + jj), r1 = r0 + 1;
      row0[q] = (r0 < NSQ) ? (r0 / NN) : ((r0 - NSQ) % NN);
      row1[q] = (r1 < NSQ) ? (r1 / NN) : ((r1 - NSQ) % NN);
      aokf[q] = ((j < NN) && adj[(b * NN + i) * NN + jj] > 0) ? 1.f : 0.f;
    }
  }

  float acc0[3] = {0.f, 0.f, 0.f}, acc1[3] = {0.f, 0.f, 0.f};
#pragma unroll
  for (int tk = 0; tk < 3; ++tk) {
    const int t = wid + 4 * tk;
    const unsigned* xst = au + t * NN;
    float xr00[4], xr01[4], xr10[4], xr11[4], xj0[4], xj1[4];
#pragma unroll
    for (int q = 0; q < 4; ++q) {
      int j = lane + 64 * q; if (j >= NN) j = 0;
      const unsigned u0 = xst[row0[q]], u1 = xst[row1[q]], uj = xst[j];
      xr00[q] = lo_f(u0); xr01[q] = hi_f(u0);
      xr10[q] = lo_f(u1); xr11[q] = hi_f(u1);
      xj0[q]  = lo_f(uj); xj1[q]  = hi_f(uj);
    }
#pragma unroll 1
    for (int h = 0; h < NGH; ++h) {
      const float w0 = lds[A_GW + h*8 + 0], w1_ = lds[A_GW + h*8 + 1];
      const float w2_= lds[A_GW + h*8 + 2], w3  = lds[A_GW + h*8 + 3];
      const float w4 = lds[A_GW + h*8 + 4], w5  = lds[A_GW + h*8 + 5];
      const float w6 = lds[A_GW + h*8 + 6], w7  = lds[A_GW + h*8 + 7];
      const float a0 = lds[A_GW + 64 + h*2], a1 = lds[A_GW + 64 + h*2 + 1];
      float s0 = 0.f, s1 = 0.f, s2 = 0.f;
#pragma unroll
      for (int q = 0; q < 4; ++q) {
        float wx0 = xr00[q]*w0 + xr01[q]*w2_ + xr10[q]*w4 + xr11[q]*w6;
        float wx1 = xr00[q]*w1_ + xr01[q]*w3 + xr10[q]*w5 + xr11[q]*w7;
        wx0 = (wx0 > 0.f) ? wx0 : GALPHA * wx0;
        wx1 = (wx1 > 0.f) ? wx1 : GALPHA * wx1;
        float e = a0 * wx0 + a1 * wx1;
        e = (aokf[q] > 0.f) ? e : GNEG;       // exp(GNEG) underflows to exactly 0
        const float ex = __expf(e);           // |e| <= ~10 unmasked: no overflow w/o max-sub
        s0 += ex; s1 += ex * xj0[q]; s2 += ex * xj1[q];
      }
      s0 = wave_sum(s0); s1 = wave_sum(s1); s2 = wave_sum(s2);
      const float inv = __builtin_amdgcn_rcpf(s0);
      acc0[tk] += tanh_fast(s1 * inv + lds[A_GW + 80 + h*2]);
      acc1[tk] += tanh_fast(s2 * inv + lds[A_GW + 80 + h*2 + 1]);
    }
  }

  // conv1 epilogue -> out0[bn][t][e] (bf16)
  {
    const float c1w0 = conv1_w[lane],       c1w1 = conv1_w[64 + lane];
    const float c1w2 = conv1_w[128 + lane], c1w3 = conv1_w[192 + lane];
    const float c1b  = conv1_b[lane];
#pragma unroll
    for (int tk = 0; tk < 3; ++tk) {
      const int t = wid + 4 * tk;
      const unsigned up = au[t * NN + i];
      const float g0 = acc0[tk] * (1.f / NGH), g1 = acc1[tk] * (1.f / NGH);
      out0[bn*768 + t*EE + lane] =
          bf16u(lo_f(up)*c1w0 + hi_f(up)*c1w1 + g0*c1w2 + g1*c1w3 + c1b);
    }
  }
}

// ===========================================================================
// Kernel B: 2-layer transformer + final convs. One block per (b,n).
// Wave owns t-triple; residual stream in registers; f32 weights (no unpack).
// ===========================================================================
__global__ __launch_bounds__(256) void xf_final_kernel(
    const unsigned short* __restrict__ out0,  // bf16 (B,N,T,E)
    const float* __restrict__ wb,             // f32 transposed weights (prep)
    const float* __restrict__ temb,
    const float* __restrict__ bo,
    const float* __restrict__ ln1_g, const float* __restrict__ ln1_b,
    const float* __restrict__ ln2_g, const float* __restrict__ ln2_b,
    const float* __restrict__ ff_b1, const float* __restrict__ ff_b2,
    const float* __restrict__ lng, const float* __restrict__ lnb,
    const float* __restrict__ conv2_w, const float* __restrict__ conv2_b,
    const float* __restrict__ conv3_w, const float* __restrict__ conv3_b,
    float* __restrict__ fout)
{
  __shared__ float lds[L_TOTB];
  unsigned*       au   = (unsigned*)lds;
  unsigned short* sh16 = (unsigned short*)lds;

  const int bn   = blockIdx.x;
  const int tid  = threadIdx.x;
  const int lane = tid & 63;
  const int wid  = tid >> 6;
  const int t0   = 3 * wid;

  float outv[3];
#pragma unroll
  for (int tt = 0; tt < 3; ++tt)
    outv[tt] = b16f(out0[bn*768 + (t0 + tt)*EE + lane]);

  for (int l = 0; l < 2; ++l) {
    const float* wqt = wb + l*4096;
    const float* wkt = wb + 8192  + l*4096;
    const float* wvt = wb + 16384 + l*4096;
    const float* wot = wb + 24576 + l*4096;
    const float* w1t = wb + 32768 + l*16384;
    const float* w2t = wb + 65536 + l*16384;

    __syncthreads();   // bar A: prior-layer FF reads done before QB-region writes

    // qq = out + temb (registers + LDS for cross-lane QKV reads)
    float qqv[3];
#pragma unroll
    for (int tt = 0; tt < 3; ++tt) {
      qqv[tt] = outv[tt] + temb[(t0 + tt)*EE + lane];
      lds[L_QQ + (t0 + tt)*SRD + lane] = qqv[tt];
    }

    // ---- QKV: lane owns col c, wave owns t-triple ----
    {
      const int c = lane;
      float aq[3] = {0,0,0}, ak[3] = {0,0,0}, av[3] = {0,0,0};
      const float* wqp = wqt + c*8;
      const float* wkp = wkt + c*8;
      const float* wvp = wvt + c*8;
#pragma unroll 1
      for (int kb = 0; kb < 8; ++kb) {
        float wq8[8], wk8[8], wv8[8];
        *(float4*)&wq8[0] = *(const float4*)(wqp + kb*512);
        *(float4*)&wq8[4] = *(const float4*)(wqp + kb*512 + 4);
        *(float4*)&wk8[0] = *(const float4*)(wkp + kb*512);
        *(float4*)&wk8[4] = *(const float4*)(wkp + kb*512 + 4);
        *(float4*)&wv8[0] = *(const float4*)(wvp + kb*512);
        *(float4*)&wv8[4] = *(const float4*)(wvp + kb*512 + 4);
        float a[3][8];
#pragma unroll
        for (int tt = 0; tt < 3; ++tt) {
          *(float4*)&a[tt][0] = *(const float4*)&lds[L_QQ + (t0+tt)*SRD + 8*kb];
          *(float4*)&a[tt][4] = *(const float4*)&lds[L_QQ + (t0+tt)*SRD + 8*kb + 4];
        }
#pragma unroll
        for (int tt = 0; tt < 3; ++tt)
#pragma unroll
          for (int j = 0; j < 8; ++j) {
            aq[tt] += a[tt][j]*wq8[j];
            ak[tt] += a[tt][j]*wk8[j];
            av[tt] += a[tt][j]*wv8[j];
          }
      }
#pragma unroll
      for (int tt = 0; tt < 3; ++tt) {
        const int t = t0 + tt;
        sh16[2*L_QB + t*SRD16 + c] = bf16u(aq[tt]);
        sh16[2*L_KB + t*SRD16 + c] = bf16u(ak[tt]);
        sh16[2*L_VB + t*SRD16 + c] = bf16u(av[tt]);
      }
    }
    __syncthreads();   // bar B

    // ---- Attention: wave h owns head h (wave-local) ----
    {
      const int h = wid;
      if (lane < 48) {
        const int t = lane >> 2, s0 = 3*(lane & 3);
        float qf[16];
        {
          const uint4 qa = *(const uint4*)&sh16[2*L_QB + t*SRD16 + h*16];
          const uint4 qb = *(const uint4*)&sh16[2*L_QB + t*SRD16 + h*16 + 8];
          UNPK8(qa, qf); UNPK8(qb, qf + 8);
        }
#pragma unroll
        for (int ss = 0; ss < 3; ++ss) {
          const int s = s0 + ss;
          float d = 0.f;
          {
            const uint4 ka = *(const uint4*)&sh16[2*L_KB + s*SRD16 + h*16];
            float kf[8]; UNPK8(ka, kf);
#pragma unroll
            for (int xq = 0; xq < 8; ++xq) d += qf[xq]*kf[xq];
          }
          {
            const uint4 kc = *(const uint4*)&sh16[2*L_KB + s*SRD16 + h*16 + 8];
            float kf[8]; UNPK8(kc, kf);
#pragma unroll
            for (int xq = 0; xq < 8; ++xq) d += qf[8+xq]*kf[xq];
          }
          lds[L_SC + h*144 + t*12 + s] = d * 0.25f;
        }
      }
      __builtin_amdgcn_wave_barrier();
      if (lane < 12) {
        float* row = &lds[L_SC + h*144 + lane*12];
        float m = row[0];
#pragma unroll
        for (int s = 1; s < 12; ++s) m = fmaxf(m, row[s]);
        float ex[12]; float sum = 0.f;
#pragma unroll
        for (int s = 0; s < 12; ++s) { ex[s] = __expf(row[s] - m); sum += ex[s]; }
        const float inv = __builtin_amdgcn_rcpf(sum);
#pragma unroll
        for (int s = 0; s < 12; ++s) row[s] = ex[s] * inv;
      }
      __builtin_amdgcn_wave_barrier();
      {
        const int d = lane & 15, tq = lane >> 4;
#pragma unroll
        for (int tt = 0; tt < 3; ++tt) {
          const int t = tq + 4*tt;
          float cacc = 0.f;
#pragma unroll
          for (int s = 0; s < 12; ++s) {
            const float p = lds[L_SC + h*144 + t*12 + s];
            const unsigned uv = au[L_VB + s*36 + h*8 + (d >> 1)];
            cacc += p * ((d & 1) ? hi_f(uv) : lo_f(uv));
          }
          lds[L_CTX + t*SRD + h*16 + d] = cacc;
        }
      }
    }
    __syncthreads();   // bar C

    // ---- Wo + bias + residual(qq) -> LN1 -> X1 ----
    {
      float acc[3] = {0,0,0};
      const float* wop = wot + lane*8;
#pragma unroll 1
      for (int kb = 0; kb < 8; ++kb) {
        float w8[8];
        *(float4*)&w8[0] = *(const float4*)(wop + kb*512);
        *(float4*)&w8[4] = *(const float4*)(wop + kb*512 + 4);
        float a[3][8];
#pragma unroll
        for (int tt = 0; tt < 3; ++tt) {
          *(float4*)&a[tt][0] = *(const float4*)&lds[L_CTX + (t0+tt)*SRD + 8*kb];
          *(float4*)&a[tt][4] = *(const float4*)&lds[L_CTX + (t0+tt)*SRD + 8*kb + 4];
        }
#pragma unroll
        for (int tt = 0; tt < 3; ++tt)
#pragma unroll
          for (int j = 0; j < 8; ++j) acc[tt] += a[tt][j]*w8[j];
      }
#pragma unroll
      for (int tt = 0; tt < 3; ++tt) {
        float v = acc[tt] + bo[l*EE + lane] + qqv[tt];
        const float mu = wave_sum(v) * (1.f/64);
        const float dd = v - mu;
        const float var = wave_sum(dd*dd) * (1.f/64);
        lds[L_X1 + (t0+tt)*SRD + lane] =
            dd * rsqrtf(var + 1e-5f) * ln1_g[l*EE + lane] + ln1_b[l*EE + lane];
      }
    }
    __syncthreads();   // bar D: all CTX reads done before FF clobbers the region

    // ---- FF1 + relu -> FF (f32) : lane owns f-quad, wave owns t-triple ----
    {
      const int f0 = 4*lane;
      float ac[4][3] = {};
#pragma unroll 1
      for (int kb = 0; kb < 8; ++kb) {
        float a[3][8];
#pragma unroll
        for (int tt = 0; tt < 3; ++tt) {
          *(float4*)&a[tt][0] = *(const float4*)&lds[L_X1 + (t0+tt)*SRD + 8*kb];
          *(float4*)&a[tt][4] = *(const float4*)&lds[L_X1 + (t0+tt)*SRD + 8*kb + 4];
        }
#pragma unroll
        for (int ff = 0; ff < 4; ++ff) {
          float wf[8];
          *(float4*)&wf[0] = *(const float4*)(w1t + kb*2048 + (f0+ff)*8);
          *(float4*)&wf[4] = *(const float4*)(w1t + kb*2048 + (f0+ff)*8 + 4);
#pragma unroll
          for (int tt = 0; tt < 3; ++tt)
#pragma unroll
            for (int j = 0; j < 8; ++j) ac[ff][tt] += a[tt][j]*wf[j];
        }
      }
      const float4 bv = *(const float4*)&ff_b1[l*FFD + f0];
#pragma unroll
      for (int tt = 0; tt < 3; ++tt) {
        *(float4*)&lds[L_FF + (t0+tt)*FSRD + f0] = make_float4(
            fmaxf(ac[0][tt] + bv.x, 0.f), fmaxf(ac[1][tt] + bv.y, 0.f),
            fmaxf(ac[2][tt] + bv.z, 0.f), fmaxf(ac[3][tt] + bv.w, 0.f));
      }
    }
    // FF1 -> FF2 is wave-local (same wave wrote all 256 f of its t-triple)

    // ---- FF2 + b2 + residual(X1) -> LN2 -> +out -> LN3 (all wave-local) ----
    {
      float acc[3] = {0,0,0};
      const float* w2p = w2t + lane*8;
#pragma unroll 1
      for (int kb = 0; kb < 32; ++kb) {
        float w8[8];
        *(float4*)&w8[0] = *(const float4*)(w2p + kb*512);
        *(float4*)&w8[4] = *(const float4*)(w2p + kb*512 + 4);
        float a[3][8];
#pragma unroll
        for (int tt = 0; tt < 3; ++tt) {
          *(float4*)&a[tt][0] = *(const float4*)&lds[L_FF + (t0+tt)*FSRD + 8*kb];
          *(float4*)&a[tt][4] = *(const float4*)&lds[L_FF + (t0+tt)*FSRD + 8*kb + 4];
        }
#pragma unroll
        for (int tt = 0; tt < 3; ++tt)
#pragma unroll
          for (int j = 0; j < 8; ++j) acc[tt] += a[tt][j]*w8[j];
      }
#pragma unroll
      for (int tt = 0; tt < 3; ++tt) {
        float v = acc[tt] + ff_b2[l*EE + lane] + lds[L_X1 + (t0+tt)*SRD + lane];
        float mu = wave_sum(v) * (1.f/64);
        float dd = v - mu;
        float var = wave_sum(dd*dd) * (1.f/64);
        const float blk = dd * rsqrtf(var + 1e-5f) * ln2_g[l*EE + lane] + ln2_b[l*EE + lane];
        float w = blk + outv[tt];
        mu = wave_sum(w) * (1.f/64);
        dd = w - mu;
        var = wave_sum(dd*dd) * (1.f/64);
        outv[tt] = dd * rsqrtf(var + 1e-5f) * lng[l*EE + lane] + lnb[l*EE + lane];
      }
    }
  }

  // stage final residual stream (QQ region is free; no FF overlap)
#pragma unroll
  for (int tt = 0; tt < 3; ++tt)
    lds[L_QQ + (t0+tt)*SRD + lane] = outv[tt];
  __syncthreads();

  // final conv2 (time mix) + relu + conv3 (embed contraction)
  float xt[12];
#pragma unroll
  for (int t = 0; t < 12; ++t) xt[t] = lds[L_QQ + t*SRD + lane];
  const float c3w = conv3_w[lane];
  for (int o = wid; o < 12; o += 4) {
    float a = conv2_b[o];
#pragma unroll
    for (int t = 0; t < 12; ++t) a += xt[t] * conv2_w[o*TT + t];
    a = fmaxf(a, 0.f);
    const float s = wave_sum(a * c3w);
    if (lane == 0) fout[bn*TT + o] = s + conv3_b[0];
  }
}

// ---------------------------------------------------------------------------
extern "C" void kernel_launch(void* const* d_in, const int* in_sizes, int n_in,
                              void* d_out, int out_size, void* d_ws, size_t ws_size,
                              hipStream_t stream) {
  const float* x       = (const float*)d_in[0];
  const int*   adj     = (const int*)  d_in[1];
  const float* gat_W2  = (const float*)d_in[2];
  const float* gat_a   = (const float*)d_in[3];
  const float* gat_b   = (const float*)d_in[4];
  const float* conv1_w = (const float*)d_in[5];
  const float* conv1_b = (const float*)d_in[6];
  const float* temb    = (const float*)d_in[7];
  const float* Wq      = (const float*)d_in[8];
  const float* Wk      = (const float*)d_in[9];
  const float* Wv      = (const float*)d_in[10];
  const float* Wo      = (const float*)d_in[11];
  const float* bo      = (const float*)d_in[12];
  const float* ln1_g   = (const float*)d_in[13];
  const float* ln1_b   = (const float*)d_in[14];
  const float* ln2_g   = (const float*)d_in[15];
  const float* ln2_b   = (const float*)d_in[16];
  const float* ff_w1   = (const float*)d_in[17];
  const float* ff_b1   = (const float*)d_in[18];
  const float* ff_w2   = (const float*)d_in[19];
  const float* ff_b2   = (const float*)d_in[20];
  const float* lng     = (const float*)d_in[21];
  const float* lnb     = (const float*)d_in[22];
  const float* conv2_w = (const float*)d_in[23];
  const float* conv2_b = (const float*)d_in[24];
  const float* conv3_w = (const float*)d_in[25];
  const float* conv3_b = (const float*)d_in[26];

  float* wbf = (float*)d_ws;                                  // 98304 f32
  unsigned short* out0 = (unsigned short*)(wbf + 98304);      // 8*207*768 bf16
  float* fout = (float*)d_out;

  prep_weights<<<384, 256, 0, stream>>>(Wq, Wk, Wv, Wo, ff_w1, ff_w2, wbf);

  gat_conv1_kernel<<<BB*NN, 256, 0, stream>>>(
      x, adj, gat_W2, gat_a, gat_b, conv1_w, conv1_b, out0);

  xf_final_kernel<<<BB*NN, 256, 0, stream>>>(
      out0, wbf, temb, bo, ln1_g, ln1_b, ln2_g, ln2_b,
      ff_b1, ff_b2, lng, lnb, conv2_w, conv2_b, conv3_w, conv3_b, fout);
}

// Round 11
// 283.886 us; speedup vs baseline: 1.2373x; 1.2373x over previous
//
#include <hip/hip_runtime.h>
#include <hip/hip_bf16.h>

#define NN   207
#define BB   8
#define TT   12
#define EE   64
#define FFD  256
#define NGH  8
#define GALPHA 0.2f
#define GNEG  -9e15f

// ---- Kernel B LDS layout (f32 units) ----
#define SRD   68      // f32 row stride (bank-safe, 16B-aligned)
#define SRD16 72      // bf16 row stride (u16 units)
#define FSRD  264     // FF f32 row stride
#define L_QQ  0       // [12][68]
#define L_X1  816     // [12][68]
#define L_QB  1632    // bf16 [12][72] (u16@2*L_QB)
#define L_KB  2064
#define L_VB  2496
#define L_SC  2928    // 4 heads * 144
#define L_CTX 3504    // [12][68] -> ends 4320
#define L_FF  1632    // alias over QB..CTX (dead there), [12][264] -> ends 4800
#define L_TOTB 4800   // 19200 B

__device__ __forceinline__ float lo_f(unsigned u) { return __uint_as_float(u << 16); }
__device__ __forceinline__ float hi_f(unsigned u) { return __uint_as_float(u & 0xffff0000u); }
__device__ __forceinline__ float b16f(unsigned short s) { return __uint_as_float(((unsigned)s) << 16); }
__device__ __forceinline__ unsigned pk2(float a, float b) {
  unsigned la = (unsigned)__bfloat16_as_ushort(__float2bfloat16(a));
  unsigned lb = (unsigned)__bfloat16_as_ushort(__float2bfloat16(b));
  return la | (lb << 16);
}
__device__ __forceinline__ unsigned short bf16u(float a) {
  return __bfloat16_as_ushort(__float2bfloat16(a));
}
__device__ __forceinline__ float tanh_fast(float x) {
  // tanh(x) = 1 - 2/(e^{2x}+1); v_rcp ~1ulp, well within tolerance
  return 1.f - 2.f * __builtin_amdgcn_rcpf(__expf(2.f * x) + 1.f);
}

// ---- DPP wave reduction: row_ror 1,2,4,8 (in-row sums) + readlane combine ----
// HW-verified in round 8 (absmax unchanged).
__device__ __forceinline__ float row16_sum(float v) {
  v += __int_as_float(__builtin_amdgcn_update_dpp(0, __float_as_int(v), 0x121, 0xf, 0xf, false));
  v += __int_as_float(__builtin_amdgcn_update_dpp(0, __float_as_int(v), 0x122, 0xf, 0xf, false));
  v += __int_as_float(__builtin_amdgcn_update_dpp(0, __float_as_int(v), 0x124, 0xf, 0xf, false));
  v += __int_as_float(__builtin_amdgcn_update_dpp(0, __float_as_int(v), 0x128, 0xf, 0xf, false));
  return v;
}
__device__ __forceinline__ float wave_sum(float v) {
  const float r = row16_sum(v);
  const float a = __int_as_float(__builtin_amdgcn_readlane(__float_as_int(r), 0));
  const float b = __int_as_float(__builtin_amdgcn_readlane(__float_as_int(r), 16));
  const float c = __int_as_float(__builtin_amdgcn_readlane(__float_as_int(r), 32));
  const float d = __int_as_float(__builtin_amdgcn_readlane(__float_as_int(r), 48));
  return (a + b) + (c + d);
}
#define UNPK8(U, f) { (f)[0]=lo_f((U).x); (f)[1]=hi_f((U).x); (f)[2]=lo_f((U).y); (f)[3]=hi_f((U).y); \
                      (f)[4]=lo_f((U).z); (f)[5]=hi_f((U).z); (f)[6]=lo_f((U).w); (f)[7]=hi_f((U).w); }

// ===========================================================================
// Workspace (u16 from d_ws): wb[98304] bf16 weights, then out0 bf16[8*207*768].
// Total 2.74 MB < 5.09 MB proven watermark.
// ===========================================================================

// ===========================================================================
// Prep: bf16 transposed+kb-tiled weights (round-7 proven layout).
// (u16 idx): QT/KT/VT/OT: which*8192 + l*4096 + kb*512 + c*8 + j  (k=8kb+j)
//   W1T: 32768 + l*16384 + kb*2048 + f*8 + j      (kb 0..7)
//   W2T: 65536 + l*16384 + kb*512  + e*8 + j      (kb 0..31)
// ===========================================================================
__global__ __launch_bounds__(256) void prep_weights(
    const float* __restrict__ Wq, const float* __restrict__ Wk,
    const float* __restrict__ Wv, const float* __restrict__ Wo,
    const float* __restrict__ ff_w1, const float* __restrict__ ff_w2,
    unsigned short* __restrict__ wb)
{
  const int idx = blockIdx.x * 256 + threadIdx.x;   // < 98304
  float v;
  if (idx < 32768) {
    const int which = idx >> 13;
    const int r = idx & 8191;
    const int l = r >> 12, q = r & 4095;
    const int kb = q >> 9, c = (q >> 3) & 63, j = q & 7;
    const float* W = (which == 0) ? Wq : (which == 1) ? Wk : (which == 2) ? Wv : Wo;
    v = W[l*4096 + (8*kb + j)*64 + c];
  } else if (idx < 65536) {
    const int r = idx - 32768;
    const int l = r >> 14, q = r & 16383;
    const int kb = q >> 11, f = (q >> 3) & 255, j = q & 7;
    v = ff_w1[l*16384 + (8*kb + j)*256 + f];
  } else {
    const int r = idx - 65536;
    const int l = r >> 14, q = r & 16383;
    const int kb = q >> 9, e = (q >> 3) & 63, j = q & 7;
    v = ff_w2[l*16384 + (8*kb + j)*64 + e];
  }
  wb[idx] = bf16u(v);
}

// ===========================================================================
// Kernel A: GAT (8 heads) + conv1. One block per (b, n). Writes out0 bf16.
// h-OUTER loop: all LDS gathers hoisted (72 regs); each h-iter has 12
// independent exp chains + 9 independent reduction chains (3x ILP).
// ===========================================================================
#define A_GW 2484   // u32 xs_pk[12][207] then 96 floats of GAT params

__global__ __launch_bounds__(256) void gat_conv1_kernel(
    const float* __restrict__ x,        const int* __restrict__ adj,
    const float* __restrict__ gat_W2,   const float* __restrict__ gat_a,
    const float* __restrict__ gat_b,    const float* __restrict__ conv1_w,
    const float* __restrict__ conv1_b,  unsigned short* __restrict__ out0)
{
  __shared__ float lds[A_GW + 96];
  unsigned* au = (unsigned*)lds;

  const int bn   = blockIdx.x;
  const int b    = bn / NN;
  const int i    = bn % NN;
  const int tid  = threadIdx.x;
  const int lane = tid & 63;
  const int wid  = tid >> 6;

  const float* xb = x + b * 2 * NN * TT;
  for (int idx = tid; idx < NN * TT; idx += 256) {
    const int n = idx / TT, t = idx % TT;
    au[t * NN + n] = pk2(xb[idx], xb[NN * TT + idx]);
  }
  if (tid < 64) lds[A_GW + tid] = gat_W2[tid];
  if (tid < 16) { lds[A_GW + 64 + tid] = gat_a[tid]; lds[A_GW + 80 + tid] = gat_b[tid]; }
  __syncthreads();

  float aokf[4];
  int   row0[4], row1[4];
  {
    const int NSQ = NN * NN;
#pragma unroll
    for (int q = 0; q < 4; ++q) {
      const int j = lane + 64 * q;
      const int jj = (j < NN) ? j : 0;
      const int r0 = 2 * (i * NN + jj), r1 = r0 + 1;
      row0[q] = (r0 < NSQ) ? (r0 / NN) : ((r0 - NSQ) % NN);
      row1[q] = (r1 < NSQ) ? (r1 / NN) : ((r1 - NSQ) % NN);
      aokf[q] = ((j < NN) && adj[(b * NN + i) * NN + jj] > 0) ? 1.f : 0.f;
    }
  }

  // ---- hoist ALL gathers: 6 floats x 3 tk x 4 q = 72 registers ----
  float xr00[3][4], xr01[3][4], xr10[3][4], xr11[3][4], xj0[3][4], xj1[3][4];
#pragma unroll
  for (int tk = 0; tk < 3; ++tk) {
    const unsigned* xst = au + (wid + 4 * tk) * NN;
#pragma unroll
    for (int q = 0; q < 4; ++q) {
      int j = lane + 64 * q; if (j >= NN) j = 0;
      const unsigned u0 = xst[row0[q]], u1 = xst[row1[q]], uj = xst[j];
      xr00[tk][q] = lo_f(u0); xr01[tk][q] = hi_f(u0);
      xr10[tk][q] = lo_f(u1); xr11[tk][q] = hi_f(u1);
      xj0[tk][q]  = lo_f(uj); xj1[tk][q]  = hi_f(uj);
    }
  }

  float acc0[3] = {0.f, 0.f, 0.f}, acc1[3] = {0.f, 0.f, 0.f};
#pragma unroll 1
  for (int h = 0; h < NGH; ++h) {
    const float w0 = lds[A_GW + h*8 + 0], w1_ = lds[A_GW + h*8 + 1];
    const float w2_= lds[A_GW + h*8 + 2], w3  = lds[A_GW + h*8 + 3];
    const float w4 = lds[A_GW + h*8 + 4], w5  = lds[A_GW + h*8 + 5];
    const float w6 = lds[A_GW + h*8 + 6], w7  = lds[A_GW + h*8 + 7];
    const float a0 = lds[A_GW + 64 + h*2], a1 = lds[A_GW + 64 + h*2 + 1];
    const float gb0 = lds[A_GW + 80 + h*2], gb1 = lds[A_GW + 80 + h*2 + 1];
    float s0[3] = {0.f,0.f,0.f}, s1[3] = {0.f,0.f,0.f}, s2[3] = {0.f,0.f,0.f};
#pragma unroll
    for (int tk = 0; tk < 3; ++tk) {
#pragma unroll
      for (int q = 0; q < 4; ++q) {
        float wx0 = xr00[tk][q]*w0 + xr01[tk][q]*w2_ + xr10[tk][q]*w4 + xr11[tk][q]*w6;
        float wx1 = xr00[tk][q]*w1_ + xr01[tk][q]*w3 + xr10[tk][q]*w5 + xr11[tk][q]*w7;
        wx0 = (wx0 > 0.f) ? wx0 : GALPHA * wx0;
        wx1 = (wx1 > 0.f) ? wx1 : GALPHA * wx1;
        float e = a0 * wx0 + a1 * wx1;
        e = (aokf[q] > 0.f) ? e : GNEG;       // exp(GNEG) underflows to exactly 0
        const float ex = __expf(e);           // |e| small unmasked: safe w/o max-sub
        s0[tk] += ex; s1[tk] += ex * xj0[tk][q]; s2[tk] += ex * xj1[tk][q];
      }
    }
#pragma unroll
    for (int tk = 0; tk < 3; ++tk) {
      const float d0 = wave_sum(s0[tk]);
      const float d1 = wave_sum(s1[tk]);
      const float d2 = wave_sum(s2[tk]);
      const float inv = __builtin_amdgcn_rcpf(d0);
      acc0[tk] += tanh_fast(d1 * inv + gb0);
      acc1[tk] += tanh_fast(d2 * inv + gb1);
    }
  }

  // conv1 epilogue -> out0[bn][t][e] (bf16)
  {
    const float c1w0 = conv1_w[lane],       c1w1 = conv1_w[64 + lane];
    const float c1w2 = conv1_w[128 + lane], c1w3 = conv1_w[192 + lane];
    const float c1b  = conv1_b[lane];
#pragma unroll
    for (int tk = 0; tk < 3; ++tk) {
      const int t = wid + 4 * tk;
      const unsigned up = au[t * NN + i];
      const float g0 = acc0[tk] * (1.f / NGH), g1 = acc1[tk] * (1.f / NGH);
      out0[bn*768 + t*EE + lane] =
          bf16u(lo_f(up)*c1w0 + hi_f(up)*c1w1 + g0*c1w2 + g1*c1w3 + c1b);
    }
  }
}

// ===========================================================================
// Kernel B: 2-layer transformer + final convs. One block per (b,n).
// Round-7 proven structure: bf16 weights + unpack; DPP LN reductions.
// ===========================================================================
__global__ __launch_bounds__(256) void xf_final_kernel(
    const unsigned short* __restrict__ out0,  // bf16 (B,N,T,E)
    const unsigned short* __restrict__ wb,    // bf16 transposed weights (prep)
    const float* __restrict__ temb,
    const float* __restrict__ bo,
    const float* __restrict__ ln1_g, const float* __restrict__ ln1_b,
    const float* __restrict__ ln2_g, const float* __restrict__ ln2_b,
    const float* __restrict__ ff_b1, const float* __restrict__ ff_b2,
    const float* __restrict__ lng, const float* __restrict__ lnb,
    const float* __restrict__ conv2_w, const float* __restrict__ conv2_b,
    const float* __restrict__ conv3_w, const float* __restrict__ conv3_b,
    float* __restrict__ fout)
{
  __shared__ float lds[L_TOTB];
  unsigned*       au   = (unsigned*)lds;
  unsigned short* sh16 = (unsigned short*)lds;

  const int bn   = blockIdx.x;
  const int tid  = threadIdx.x;
  const int lane = tid & 63;
  const int wid  = tid >> 6;
  const int t0   = 3 * wid;

  float outv[3];
#pragma unroll
  for (int tt = 0; tt < 3; ++tt)
    outv[tt] = b16f(out0[bn*768 + (t0 + tt)*EE + lane]);

  for (int l = 0; l < 2; ++l) {
    const unsigned short* wqt = wb + l*4096;
    const unsigned short* wkt = wb + 8192  + l*4096;
    const unsigned short* wvt = wb + 16384 + l*4096;
    const unsigned short* wot = wb + 24576 + l*4096;
    const unsigned short* w1t = wb + 32768 + l*16384;
    const unsigned short* w2t = wb + 65536 + l*16384;

    __syncthreads();   // bar A: prior-layer FF reads done before QB-region writes

    // qq = out + temb (registers + LDS for cross-lane QKV reads)
    float qqv[3];
#pragma unroll
    for (int tt = 0; tt < 3; ++tt) {
      qqv[tt] = outv[tt] + temb[(t0 + tt)*EE + lane];
      lds[L_QQ + (t0 + tt)*SRD + lane] = qqv[tt];
    }

    // ---- QKV: lane owns col c, wave owns t-triple ----
    {
      const int c = lane;
      float aq[3] = {0,0,0}, ak[3] = {0,0,0}, av[3] = {0,0,0};
      const unsigned short* wqp = wqt + c*8;
      const unsigned short* wkp = wkt + c*8;
      const unsigned short* wvp = wvt + c*8;
#pragma unroll 1
      for (int kb = 0; kb < 8; ++kb) {
        const uint4 wq4 = *(const uint4*)(wqp + kb*512);
        const uint4 wk4 = *(const uint4*)(wkp + kb*512);
        const uint4 wv4 = *(const uint4*)(wvp + kb*512);
        float a[3][8];
#pragma unroll
        for (int tt = 0; tt < 3; ++tt) {
          *(float4*)&a[tt][0] = *(const float4*)&lds[L_QQ + (t0+tt)*SRD + 8*kb];
          *(float4*)&a[tt][4] = *(const float4*)&lds[L_QQ + (t0+tt)*SRD + 8*kb + 4];
        }
        float wf[8];
        UNPK8(wq4, wf);
#pragma unroll
        for (int tt = 0; tt < 3; ++tt)
#pragma unroll
          for (int j = 0; j < 8; ++j) aq[tt] += a[tt][j]*wf[j];
        UNPK8(wk4, wf);
#pragma unroll
        for (int tt = 0; tt < 3; ++tt)
#pragma unroll
          for (int j = 0; j < 8; ++j) ak[tt] += a[tt][j]*wf[j];
        UNPK8(wv4, wf);
#pragma unroll
        for (int tt = 0; tt < 3; ++tt)
#pragma unroll
          for (int j = 0; j < 8; ++j) av[tt] += a[tt][j]*wf[j];
      }
#pragma unroll
      for (int tt = 0; tt < 3; ++tt) {
        const int t = t0 + tt;
        sh16[2*L_QB + t*SRD16 + c] = bf16u(aq[tt]);
        sh16[2*L_KB + t*SRD16 + c] = bf16u(ak[tt]);
        sh16[2*L_VB + t*SRD16 + c] = bf16u(av[tt]);
      }
    }
    __syncthreads();   // bar B

    // ---- Attention: wave h owns head h (wave-local) ----
    {
      const int h = wid;
      if (lane < 48) {
        const int t = lane >> 2, s0 = 3*(lane & 3);
        float qf[16];
        {
          const uint4 qa = *(const uint4*)&sh16[2*L_QB + t*SRD16 + h*16];
          const uint4 qb = *(const uint4*)&sh16[2*L_QB + t*SRD16 + h*16 + 8];
          UNPK8(qa, qf); UNPK8(qb, qf + 8);
        }
#pragma unroll
        for (int ss = 0; ss < 3; ++ss) {
          const int s = s0 + ss;
          float d = 0.f;
          {
            const uint4 ka = *(const uint4*)&sh16[2*L_KB + s*SRD16 + h*16];
            float kf[8]; UNPK8(ka, kf);
#pragma unroll
            for (int xq = 0; xq < 8; ++xq) d += qf[xq]*kf[xq];
          }
          {
            const uint4 kc = *(const uint4*)&sh16[2*L_KB + s*SRD16 + h*16 + 8];
            float kf[8]; UNPK8(kc, kf);
#pragma unroll
            for (int xq = 0; xq < 8; ++xq) d += qf[8+xq]*kf[xq];
          }
          lds[L_SC + h*144 + t*12 + s] = d * 0.25f;
        }
      }
      __builtin_amdgcn_wave_barrier();
      if (lane < 12) {
        float* row = &lds[L_SC + h*144 + lane*12];
        float m = row[0];
#pragma unroll
        for (int s = 1; s < 12; ++s) m = fmaxf(m, row[s]);
        float ex[12]; float sum = 0.f;
#pragma unroll
        for (int s = 0; s < 12; ++s) { ex[s] = __expf(row[s] - m); sum += ex[s]; }
        const float inv = __builtin_amdgcn_rcpf(sum);
#pragma unroll
        for (int s = 0; s < 12; ++s) row[s] = ex[s] * inv;
      }
      __builtin_amdgcn_wave_barrier();
      {
        const int d = lane & 15, tq = lane >> 4;
#pragma unroll
        for (int tt = 0; tt < 3; ++tt) {
          const int t = tq + 4*tt;
          float cacc = 0.f;
#pragma unroll
          for (int s = 0; s < 12; ++s) {
            const float p = lds[L_SC + h*144 + t*12 + s];
            const unsigned uv = au[L_VB + s*36 + h*8 + (d >> 1)];
            cacc += p * ((d & 1) ? hi_f(uv) : lo_f(uv));
          }
          lds[L_CTX + t*SRD + h*16 + d] = cacc;
        }
      }
    }
    __syncthreads();   // bar C

    // ---- Wo + bias + residual(qq) -> LN1 -> X1 ----
    {
      float acc[3] = {0,0,0};
      const unsigned short* wop = wot + lane*8;
#pragma unroll 1
      for (int kb = 0; kb < 8; ++kb) {
        const uint4 w4 = *(const uint4*)(wop + kb*512);
        float a[3][8];
#pragma unroll
        for (int tt = 0; tt < 3; ++tt) {
          *(float4*)&a[tt][0] = *(const float4*)&lds[L_CTX + (t0+tt)*SRD + 8*kb];
          *(float4*)&a[tt][4] = *(const float4*)&lds[L_CTX + (t0+tt)*SRD + 8*kb + 4];
        }
        float wf[8]; UNPK8(w4, wf);
#pragma unroll
        for (int tt = 0; tt < 3; ++tt)
#pragma unroll
          for (int j = 0; j < 8; ++j) acc[tt] += a[tt][j]*wf[j];
      }
#pragma unroll
      for (int tt = 0; tt < 3; ++tt) {
        float v = acc[tt] + bo[l*EE + lane] + qqv[tt];
        const float mu = wave_sum(v) * (1.f/64);
        const float dd = v - mu;
        const float var = wave_sum(dd*dd) * (1.f/64);
        lds[L_X1 + (t0+tt)*SRD + lane] =
            dd * rsqrtf(var + 1e-5f) * ln1_g[l*EE + lane] + ln1_b[l*EE + lane];
      }
    }
    __syncthreads();   // bar D: all CTX reads done before FF clobbers the region

    // ---- FF1 + relu -> FF (f32) : lane owns f-quad, wave owns t-triple ----
    {
      const int f0 = 4*lane;
      float ac[4][3] = {};
#pragma unroll 1
      for (int kb = 0; kb < 8; ++kb) {
        uint4 w4[4];
#pragma unroll
        for (int ff = 0; ff < 4; ++ff)
          w4[ff] = *(const uint4*)(w1t + kb*2048 + (f0+ff)*8);
        float a[3][8];
#pragma unroll
        for (int tt = 0; tt < 3; ++tt) {
          *(float4*)&a[tt][0] = *(const float4*)&lds[L_X1 + (t0+tt)*SRD + 8*kb];
          *(float4*)&a[tt][4] = *(const float4*)&lds[L_X1 + (t0+tt)*SRD + 8*kb + 4];
        }
#pragma unroll
        for (int ff = 0; ff < 4; ++ff) {
          float wf[8]; UNPK8(w4[ff], wf);
#pragma unroll
          for (int tt = 0; tt < 3; ++tt)
#pragma unroll
            for (int j = 0; j < 8; ++j) ac[ff][tt] += a[tt][j]*wf[j];
        }
      }
      const float4 bv = *(const float4*)&ff_b1[l*FFD + f0];
#pragma unroll
      for (int tt = 0; tt < 3; ++tt) {
        *(float4*)&lds[L_FF + (t0+tt)*FSRD + f0] = make_float4(
            fmaxf(ac[0][tt] + bv.x, 0.f), fmaxf(ac[1][tt] + bv.y, 0.f),
            fmaxf(ac[2][tt] + bv.z, 0.f), fmaxf(ac[3][tt] + bv.w, 0.f));
      }
    }
    // FF1 -> FF2 is wave-local (same wave wrote all 256 f of its t-triple)

    // ---- FF2 + b2 + residual(X1) -> LN2 -> +out -> LN3 (all wave-local) ----
    {
      float acc[3] = {0,0,0};
      const unsigned short* w2p = w2t + lane*8;
#pragma unroll 1
      for (int kb = 0; kb < 32; ++kb) {
        const uint4 w4 = *(const uint4*)(w2p + kb*512);
        float a[3][8];
#pragma unroll
        for (int tt = 0; tt < 3; ++tt) {
          *(float4*)&a[tt][0] = *(const float4*)&lds[L_FF + (t0+tt)*FSRD + 8*kb];
          *(float4*)&a[tt][4] = *(const float4*)&lds[L_FF + (t0+tt)*FSRD + 8*kb + 4];
        }
        float wf[8]; UNPK8(w4, wf);
#pragma unroll
        for (int tt = 0; tt < 3; ++tt)
#pragma unroll
          for (int j = 0; j < 8; ++j) acc[tt] += a[tt][j]*wf[j];
      }
#pragma unroll
      for (int tt = 0; tt < 3; ++tt) {
        float v = acc[tt] + ff_b2[l*EE + lane] + lds[L_X1 + (t0+tt)*SRD + lane];
        float mu = wave_sum(v) * (1.f/64);
        float dd = v - mu;
        float var = wave_sum(dd*dd) * (1.f/64);
        const float blk = dd * rsqrtf(var + 1e-5f) * ln2_g[l*EE + lane] + ln2_b[l*EE + lane];
        float w = blk + outv[tt];
        mu = wave_sum(w) * (1.f/64);
        dd = w - mu;
        var = wave_sum(dd*dd) * (1.f/64);
        outv[tt] = dd * rsqrtf(var + 1e-5f) * lng[l*EE + lane] + lnb[l*EE + lane];
      }
    }
  }

  // stage final residual stream (QQ region is free; no FF overlap)
#pragma unroll
  for (int tt = 0; tt < 3; ++tt)
    lds[L_QQ + (t0+tt)*SRD + lane] = outv[tt];
  __syncthreads();

  // final conv2 (time mix) + relu + conv3 (embed contraction)
  float xt[12];
#pragma unroll
  for (int t = 0; t < 12; ++t) xt[t] = lds[L_QQ + t*SRD + lane];
  const float c3w = conv3_w[lane];
  for (int o = wid; o < 12; o += 4) {
    float a = conv2_b[o];
#pragma unroll
    for (int t = 0; t < 12; ++t) a += xt[t] * conv2_w[o*TT + t];
    a = fmaxf(a, 0.f);
    const float s = wave_sum(a * c3w);
    if (lane == 0) fout[bn*TT + o] = s + conv3_b[0];
  }
}

// ---------------------------------------------------------------------------
extern "C" void kernel_launch(void* const* d_in, const int* in_sizes, int n_in,
                              void* d_out, int out_size, void* d_ws, size_t ws_size,
                              hipStream_t stream) {
  const float* x       = (const float*)d_in[0];
  const int*   adj     = (const int*)  d_in[1];
  const float* gat_W2  = (const float*)d_in[2];
  const float* gat_a   = (const float*)d_in[3];
  const float* gat_b   = (const float*)d_in[4];
  const float* conv1_w = (const float*)d_in[5];
  const float* conv1_b = (const float*)d_in[6];
  const float* temb    = (const float*)d_in[7];
  const float* Wq      = (const float*)d_in[8];
  const float* Wk      = (const float*)d_in[9];
  const float* Wv      = (const float*)d_in[10];
  const float* Wo      = (const float*)d_in[11];
  const float* bo      = (const float*)d_in[12];
  const float* ln1_g   = (const float*)d_in[13];
  const float* ln1_b   = (const float*)d_in[14];
  const float* ln2_g   = (const float*)d_in[15];
  const float* ln2_b   = (const float*)d_in[16];
  const float* ff_w1   = (const float*)d_in[17];
  const float* ff_b1   = (const float*)d_in[18];
  const float* ff_w2   = (const float*)d_in[19];
  const float* ff_b2   = (const float*)d_in[20];
  const float* lng     = (const float*)d_in[21];
  const float* lnb     = (const float*)d_in[22];
  const float* conv2_w = (const float*)d_in[23];
  const float* conv2_b = (const float*)d_in[24];
  const float* conv3_w = (const float*)d_in[25];
  const float* conv3_b = (const float*)d_in[26];

  unsigned short* wb   = (unsigned short*)d_ws;          // 98304 u16
  unsigned short* out0 = wb + 98304;                     // 8*207*768 u16 bf16
  float* fout = (float*)d_out;

  prep_weights<<<384, 256, 0, stream>>>(Wq, Wk, Wv, Wo, ff_w1, ff_w2, wb);

  gat_conv1_kernel<<<BB*NN, 256, 0, stream>>>(
      x, adj, gat_W2, gat_a, gat_b, conv1_w, conv1_b, out0);

  xf_final_kernel<<<BB*NN, 256, 0, stream>>>(
      out0, wb, temb, bo, ln1_g, ln1_b, ln2_g, ln2_b,
      ff_b1, ff_b2, lng, lnb, conv2_w, conv2_b, conv3_w, conv3_b, fout);
}

// Round 12
// 235.976 us; speedup vs baseline: 1.4886x; 1.2030x over previous
//
#include <hip/hip_runtime.h>
#include <hip/hip_bf16.h>
#include <hip/hip_fp16.h>

#define NN   207
#define BB   8
#define TT   12
#define EE   64
#define FFD  256
#define NGH  8
#define GALPHA 0.2f
#define GNEG  -9e15f

// ---- Kernel B LDS layout ----
// u16-unit offsets (all ≡0 mod 8 → 16B aligned)
#define U_QQ  0       // f16 [12][72]
#define U_X1  864     // f16 [12][72]
#define U_QB  1728    // f16 [12][72]
#define U_KB  2592
#define U_VB  3456
#define F_SC  2160    // f32 units (byte 8640): f32 [4][144]
#define U_CTX 5472    // f16 [12][72]
#define U_FF  6336    // f16 [12][264]
#define F_FIN 3168    // f32 units (byte 12672), aliases U_FF (dead at final)
#define LDS_F32 4752  // 19008 B

__device__ __forceinline__ float lo_f(unsigned u) { return __uint_as_float(u << 16); }
__device__ __forceinline__ float hi_f(unsigned u) { return __uint_as_float(u & 0xffff0000u); }
__device__ __forceinline__ unsigned pk2(float a, float b) {
  unsigned la = (unsigned)__bfloat16_as_ushort(__float2bfloat16(a));
  unsigned lb = (unsigned)__bfloat16_as_ushort(__float2bfloat16(b));
  return la | (lb << 16);
}
__device__ __forceinline__ unsigned short h16u(float a) {
  return __half_as_ushort(__float2half(a));
}
__device__ __forceinline__ float u16f(unsigned short s) {
  return __half2float(__ushort_as_half(s));
}
__device__ __forceinline__ float tanh_fast(float x) {
  return 1.f - 2.f * __builtin_amdgcn_rcpf(__expf(2.f * x) + 1.f);
}

// ---- DPP wave reduction (HW-verified rounds 8/10) ----
__device__ __forceinline__ float row16_sum(float v) {
  v += __int_as_float(__builtin_amdgcn_update_dpp(0, __float_as_int(v), 0x121, 0xf, 0xf, false));
  v += __int_as_float(__builtin_amdgcn_update_dpp(0, __float_as_int(v), 0x122, 0xf, 0xf, false));
  v += __int_as_float(__builtin_amdgcn_update_dpp(0, __float_as_int(v), 0x124, 0xf, 0xf, false));
  v += __int_as_float(__builtin_amdgcn_update_dpp(0, __float_as_int(v), 0x128, 0xf, 0xf, false));
  return v;
}
__device__ __forceinline__ float wave_sum(float v) {
  const float r = row16_sum(v);
  const float a = __int_as_float(__builtin_amdgcn_readlane(__float_as_int(r), 0));
  const float b = __int_as_float(__builtin_amdgcn_readlane(__float_as_int(r), 16));
  const float c = __int_as_float(__builtin_amdgcn_readlane(__float_as_int(r), 32));
  const float d = __int_as_float(__builtin_amdgcn_readlane(__float_as_int(r), 48));
  return (a + b) + (c + d);
}

// ===========================================================================
// Workspace (u16 from d_ws): wb[98304] f16 weights, then out0 f16[8*207*768].
// Total 2.74 MB < 5.09 MB proven watermark.
// ===========================================================================

// ===========================================================================
// Prep: f16 transposed+kb-tiled weights (round-7 layout, f16 payload).
// (u16 idx): QT/KT/VT/OT: which*8192 + l*4096 + kb*512 + c*8 + j  (k=8kb+j)
//   W1T: 32768 + l*16384 + kb*2048 + f*8 + j      (kb 0..7)
//   W2T: 65536 + l*16384 + kb*512  + e*8 + j      (kb 0..31)
// ===========================================================================
__global__ __launch_bounds__(256) void prep_weights(
    const float* __restrict__ Wq, const float* __restrict__ Wk,
    const float* __restrict__ Wv, const float* __restrict__ Wo,
    const float* __restrict__ ff_w1, const float* __restrict__ ff_w2,
    unsigned short* __restrict__ wb)
{
  const int idx = blockIdx.x * 256 + threadIdx.x;   // < 98304
  float v;
  if (idx < 32768) {
    const int which = idx >> 13;
    const int r = idx & 8191;
    const int l = r >> 12, q = r & 4095;
    const int kb = q >> 9, c = (q >> 3) & 63, j = q & 7;
    const float* W = (which == 0) ? Wq : (which == 1) ? Wk : (which == 2) ? Wv : Wo;
    v = W[l*4096 + (8*kb + j)*64 + c];
  } else if (idx < 65536) {
    const int r = idx - 32768;
    const int l = r >> 14, q = r & 16383;
    const int kb = q >> 11, f = (q >> 3) & 255, j = q & 7;
    v = ff_w1[l*16384 + (8*kb + j)*256 + f];
  } else {
    const int r = idx - 65536;
    const int l = r >> 14, q = r & 16383;
    const int kb = q >> 9, e = (q >> 3) & 63, j = q & 7;
    v = ff_w2[l*16384 + (8*kb + j)*64 + e];
  }
  wb[idx] = h16u(v);
}

// ===========================================================================
// Kernel A: GAT (8 heads) + conv1 (round-10 proven). Writes out0 f16.
// ===========================================================================
#define A_GW 2484   // u32 xs_pk[12][207] then 96 floats of GAT params

__global__ __launch_bounds__(256) void gat_conv1_kernel(
    const float* __restrict__ x,        const int* __restrict__ adj,
    const float* __restrict__ gat_W2,   const float* __restrict__ gat_a,
    const float* __restrict__ gat_b,    const float* __restrict__ conv1_w,
    const float* __restrict__ conv1_b,  unsigned short* __restrict__ out0)
{
  __shared__ float lds[A_GW + 96];
  unsigned* au = (unsigned*)lds;

  const int bn   = blockIdx.x;
  const int b    = bn / NN;
  const int i    = bn % NN;
  const int tid  = threadIdx.x;
  const int lane = tid & 63;
  const int wid  = tid >> 6;

  const float* xb = x + b * 2 * NN * TT;
  for (int idx = tid; idx < NN * TT; idx += 256) {
    const int n = idx / TT, t = idx % TT;
    au[t * NN + n] = pk2(xb[idx], xb[NN * TT + idx]);
  }
  if (tid < 64) lds[A_GW + tid] = gat_W2[tid];
  if (tid < 16) { lds[A_GW + 64 + tid] = gat_a[tid]; lds[A_GW + 80 + tid] = gat_b[tid]; }
  __syncthreads();

  float aokf[4];
  int   row0[4], row1[4];
  {
    const int NSQ = NN * NN;
#pragma unroll
    for (int q = 0; q < 4; ++q) {
      const int j = lane + 64 * q;
      const int jj = (j < NN) ? j : 0;
      const int r0 = 2 * (i * NN + jj), r1 = r0 + 1;
      row0[q] = (r0 < NSQ) ? (r0 / NN) : ((r0 - NSQ) % NN);
      row1[q] = (r1 < NSQ) ? (r1 / NN) : ((r1 - NSQ) % NN);
      aokf[q] = ((j < NN) && adj[(b * NN + i) * NN + jj] > 0) ? 1.f : 0.f;
    }
  }

  float xr00[3][4], xr01[3][4], xr10[3][4], xr11[3][4], xj0[3][4], xj1[3][4];
#pragma unroll
  for (int tk = 0; tk < 3; ++tk) {
    const unsigned* xst = au + (wid + 4 * tk) * NN;
#pragma unroll
    for (int q = 0; q < 4; ++q) {
      int j = lane + 64 * q; if (j >= NN) j = 0;
      const unsigned u0 = xst[row0[q]], u1 = xst[row1[q]], uj = xst[j];
      xr00[tk][q] = lo_f(u0); xr01[tk][q] = hi_f(u0);
      xr10[tk][q] = lo_f(u1); xr11[tk][q] = hi_f(u1);
      xj0[tk][q]  = lo_f(uj); xj1[tk][q]  = hi_f(uj);
    }
  }

  float acc0[3] = {0.f, 0.f, 0.f}, acc1[3] = {0.f, 0.f, 0.f};
#pragma unroll 1
  for (int h = 0; h < NGH; ++h) {
    const float w0 = lds[A_GW + h*8 + 0], w1_ = lds[A_GW + h*8 + 1];
    const float w2_= lds[A_GW + h*8 + 2], w3  = lds[A_GW + h*8 + 3];
    const float w4 = lds[A_GW + h*8 + 4], w5  = lds[A_GW + h*8 + 5];
    const float w6 = lds[A_GW + h*8 + 6], w7  = lds[A_GW + h*8 + 7];
    const float a0 = lds[A_GW + 64 + h*2], a1 = lds[A_GW + 64 + h*2 + 1];
    const float gb0 = lds[A_GW + 80 + h*2], gb1 = lds[A_GW + 80 + h*2 + 1];
    float s0[3] = {0.f,0.f,0.f}, s1[3] = {0.f,0.f,0.f}, s2[3] = {0.f,0.f,0.f};
#pragma unroll
    for (int tk = 0; tk < 3; ++tk) {
#pragma unroll
      for (int q = 0; q < 4; ++q) {
        float wx0 = xr00[tk][q]*w0 + xr01[tk][q]*w2_ + xr10[tk][q]*w4 + xr11[tk][q]*w6;
        float wx1 = xr00[tk][q]*w1_ + xr01[tk][q]*w3 + xr10[tk][q]*w5 + xr11[tk][q]*w7;
        wx0 = (wx0 > 0.f) ? wx0 : GALPHA * wx0;
        wx1 = (wx1 > 0.f) ? wx1 : GALPHA * wx1;
        float e = a0 * wx0 + a1 * wx1;
        e = (aokf[q] > 0.f) ? e : GNEG;
        const float ex = __expf(e);
        s0[tk] += ex; s1[tk] += ex * xj0[tk][q]; s2[tk] += ex * xj1[tk][q];
      }
    }
#pragma unroll
    for (int tk = 0; tk < 3; ++tk) {
      const float d0 = wave_sum(s0[tk]);
      const float d1 = wave_sum(s1[tk]);
      const float d2 = wave_sum(s2[tk]);
      const float inv = __builtin_amdgcn_rcpf(d0);
      acc0[tk] += tanh_fast(d1 * inv + gb0);
      acc1[tk] += tanh_fast(d2 * inv + gb1);
    }
  }

  {
    const float c1w0 = conv1_w[lane],       c1w1 = conv1_w[64 + lane];
    const float c1w2 = conv1_w[128 + lane], c1w3 = conv1_w[192 + lane];
    const float c1b  = conv1_b[lane];
#pragma unroll
    for (int tk = 0; tk < 3; ++tk) {
      const int t = wid + 4 * tk;
      const unsigned up = au[t * NN + i];
      const float g0 = acc0[tk] * (1.f / NGH), g1 = acc1[tk] * (1.f / NGH);
      out0[bn*768 + t*EE + lane] =
          h16u(lo_f(up)*c1w0 + hi_f(up)*c1w1 + g0*c1w2 + g1*c1w3 + c1b);
    }
  }
}

// ===========================================================================
// Kernel B: 2-layer transformer + final convs. f16 data plane, __hfma2
// (v_pk_fma_f16) matmuls, f32 accum flushes, 2 barriers/layer.
// ===========================================================================
__global__ __launch_bounds__(256) void xf_final_kernel(
    const unsigned short* __restrict__ out0,  // f16 (B,N,T,E)
    const unsigned short* __restrict__ wb,    // f16 transposed weights
    const float* __restrict__ temb,
    const float* __restrict__ bo,
    const float* __restrict__ ln1_g, const float* __restrict__ ln1_b,
    const float* __restrict__ ln2_g, const float* __restrict__ ln2_b,
    const float* __restrict__ ff_b1, const float* __restrict__ ff_b2,
    const float* __restrict__ lng, const float* __restrict__ lnb,
    const float* __restrict__ conv2_w, const float* __restrict__ conv2_b,
    const float* __restrict__ conv3_w, const float* __restrict__ conv3_b,
    float* __restrict__ fout)
{
  __shared__ float lds[LDS_F32];
  unsigned*       au   = (unsigned*)lds;
  unsigned short* sh16 = (unsigned short*)lds;

  const int bn   = blockIdx.x;
  const int tid  = threadIdx.x;
  const int lane = tid & 63;
  const int wid  = tid >> 6;
  const int t0   = 3 * wid;

  const __half2 hz = __floats2half2_rn(0.f, 0.f);

  float outv[3];
#pragma unroll
  for (int tt = 0; tt < 3; ++tt)
    outv[tt] = u16f(out0[bn*768 + (t0 + tt)*EE + lane]);

  for (int l = 0; l < 2; ++l) {
    const unsigned short* wqt = wb + l*4096;
    const unsigned short* wkt = wb + 8192  + l*4096;
    const unsigned short* wvt = wb + 16384 + l*4096;
    const unsigned short* wot = wb + 24576 + l*4096;
    const unsigned short* w1t = wb + 32768 + l*16384;
    const unsigned short* w2t = wb + 65536 + l*16384;

    // qq = out + temb (regs + f16 LDS for same-wave QKV broadcast reads)
    float qqv[3];
#pragma unroll
    for (int tt = 0; tt < 3; ++tt) {
      qqv[tt] = outv[tt] + temb[(t0 + tt)*EE + lane];
      sh16[U_QQ + (t0 + tt)*72 + lane] = h16u(qqv[tt]);
    }

    // ---- QKV: lane owns col, wave owns t-triple (wave-local) ----
    {
      const unsigned short* wqp = wqt + lane*8;
      const unsigned short* wkp = wkt + lane*8;
      const unsigned short* wvp = wvt + lane*8;
      __half2 cq[3], ck[3], cv[3];
#pragma unroll
      for (int tt = 0; tt < 3; ++tt) { cq[tt] = hz; ck[tt] = hz; cv[tt] = hz; }
#pragma unroll 1
      for (int kb = 0; kb < 8; ++kb) {
        const uint4 wq4 = *(const uint4*)(wqp + kb*512);
        const uint4 wk4 = *(const uint4*)(wkp + kb*512);
        const uint4 wv4 = *(const uint4*)(wvp + kb*512);
        uint4 a4[3];
#pragma unroll
        for (int tt = 0; tt < 3; ++tt)
          a4[tt] = *(const uint4*)&sh16[U_QQ + (t0+tt)*72 + 8*kb];
        const __half2* wq2 = (const __half2*)&wq4;
        const __half2* wk2 = (const __half2*)&wk4;
        const __half2* wv2 = (const __half2*)&wv4;
#pragma unroll
        for (int tt = 0; tt < 3; ++tt) {
          const __half2* a2 = (const __half2*)&a4[tt];
#pragma unroll
          for (int j = 0; j < 4; ++j) {
            cq[tt] = __hfma2(a2[j], wq2[j], cq[tt]);
            ck[tt] = __hfma2(a2[j], wk2[j], ck[tt]);
            cv[tt] = __hfma2(a2[j], wv2[j], cv[tt]);
          }
        }
      }
#pragma unroll
      for (int tt = 0; tt < 3; ++tt) {
        const int t = t0 + tt;
        sh16[U_QB + t*72 + lane] = h16u(__low2float(cq[tt]) + __high2float(cq[tt]));
        sh16[U_KB + t*72 + lane] = h16u(__low2float(ck[tt]) + __high2float(ck[tt]));
        sh16[U_VB + t*72 + lane] = h16u(__low2float(cv[tt]) + __high2float(cv[tt]));
      }
    }
    __syncthreads();   // bar B: QKV visible to all waves

    // ---- Attention: wave h owns head h (wave-local) ----
    {
      const int h = wid;
      if (lane < 48) {
        const int t = lane >> 2, s0 = 3*(lane & 3);
        const uint4 qa = *(const uint4*)&sh16[U_QB + t*72 + h*16];
        const uint4 qb = *(const uint4*)&sh16[U_QB + t*72 + h*16 + 8];
        const __half2* q2a = (const __half2*)&qa;
        const __half2* q2b = (const __half2*)&qb;
#pragma unroll
        for (int ss = 0; ss < 3; ++ss) {
          const int s = s0 + ss;
          const uint4 ka = *(const uint4*)&sh16[U_KB + s*72 + h*16];
          const uint4 kc = *(const uint4*)&sh16[U_KB + s*72 + h*16 + 8];
          const __half2* k2a = (const __half2*)&ka;
          const __half2* k2b = (const __half2*)&kc;
          __half2 d2 = hz;
#pragma unroll
          for (int j = 0; j < 4; ++j) {
            d2 = __hfma2(q2a[j], k2a[j], d2);
            d2 = __hfma2(q2b[j], k2b[j], d2);
          }
          lds[F_SC + h*144 + t*12 + s] = (__low2float(d2) + __high2float(d2)) * 0.25f;
        }
      }
      __builtin_amdgcn_wave_barrier();
      if (lane < 12) {
        float* row = &lds[F_SC + h*144 + lane*12];
        float m = row[0];
#pragma unroll
        for (int s = 1; s < 12; ++s) m = fmaxf(m, row[s]);
        float ex[12]; float sum = 0.f;
#pragma unroll
        for (int s = 0; s < 12; ++s) { ex[s] = __expf(row[s] - m); sum += ex[s]; }
        const float inv = __builtin_amdgcn_rcpf(sum);
#pragma unroll
        for (int s = 0; s < 12; ++s) row[s] = ex[s] * inv;
      }
      __builtin_amdgcn_wave_barrier();
      {
        const int d = lane & 15, tq = lane >> 4;
#pragma unroll
        for (int tt = 0; tt < 3; ++tt) {
          const int t = tq + 4*tt;
          float cacc = 0.f;
#pragma unroll
          for (int s = 0; s < 12; ++s) {
            const float p = lds[F_SC + h*144 + t*12 + s];
            const unsigned uv = au[(U_VB/2) + s*36 + h*8 + (d >> 1)];
            const __half2 hv = *(const __half2*)&uv;
            cacc += p * ((d & 1) ? __high2float(hv) : __low2float(hv));
          }
          sh16[U_CTX + t*72 + h*16 + d] = h16u(cacc);
        }
      }
    }
    __syncthreads();   // bar C: ctx visible to all waves

    // ---- Wo + bias + residual(qq) -> LN1 -> X1 (f16) ----
    float x1v[3];
    {
      const unsigned short* wop = wot + lane*8;
      __half2 co[3];
#pragma unroll
      for (int tt = 0; tt < 3; ++tt) co[tt] = hz;
#pragma unroll 1
      for (int kb = 0; kb < 8; ++kb) {
        const uint4 w4 = *(const uint4*)(wop + kb*512);
        const __half2* w2_ = (const __half2*)&w4;
        uint4 a4[3];
#pragma unroll
        for (int tt = 0; tt < 3; ++tt)
          a4[tt] = *(const uint4*)&sh16[U_CTX + (t0+tt)*72 + 8*kb];
#pragma unroll
        for (int tt = 0; tt < 3; ++tt) {
          const __half2* a2 = (const __half2*)&a4[tt];
#pragma unroll
          for (int j = 0; j < 4; ++j) co[tt] = __hfma2(a2[j], w2_[j], co[tt]);
        }
      }
#pragma unroll
      for (int tt = 0; tt < 3; ++tt) {
        float v = __low2float(co[tt]) + __high2float(co[tt]) + bo[l*EE + lane] + qqv[tt];
        const float mu = wave_sum(v) * (1.f/64);
        const float dd = v - mu;
        const float var = wave_sum(dd*dd) * (1.f/64);
        x1v[tt] = dd * rsqrtf(var + 1e-5f) * ln1_g[l*EE + lane] + ln1_b[l*EE + lane];
        sh16[U_X1 + (t0+tt)*72 + lane] = h16u(x1v[tt]);
      }
    }
    // X1 -> FF1 is wave-local (same wave wrote its rows)

    // ---- FF1 + relu -> FF (f16): lane owns f-quad, wave owns t-triple ----
    {
      const int f0 = 4*lane;
      __half2 c2[4][3];
#pragma unroll
      for (int ff = 0; ff < 4; ++ff)
#pragma unroll
        for (int tt = 0; tt < 3; ++tt) c2[ff][tt] = hz;
#pragma unroll 1
      for (int kb = 0; kb < 8; ++kb) {
        uint4 w4[4];
#pragma unroll
        for (int ff = 0; ff < 4; ++ff)
          w4[ff] = *(const uint4*)(w1t + kb*2048 + (f0+ff)*8);
        uint4 a4[3];
#pragma unroll
        for (int tt = 0; tt < 3; ++tt)
          a4[tt] = *(const uint4*)&sh16[U_X1 + (t0+tt)*72 + 8*kb];
#pragma unroll
        for (int ff = 0; ff < 4; ++ff) {
          const __half2* w2_ = (const __half2*)&w4[ff];
#pragma unroll
          for (int tt = 0; tt < 3; ++tt) {
            const __half2* a2 = (const __half2*)&a4[tt];
#pragma unroll
            for (int j = 0; j < 4; ++j) c2[ff][tt] = __hfma2(a2[j], w2_[j], c2[ff][tt]);
          }
        }
      }
      const float4 bv = *(const float4*)&ff_b1[l*FFD + f0];
#pragma unroll
      for (int tt = 0; tt < 3; ++tt) {
        const float r0 = fmaxf(__low2float(c2[0][tt]) + __high2float(c2[0][tt]) + bv.x, 0.f);
        const float r1 = fmaxf(__low2float(c2[1][tt]) + __high2float(c2[1][tt]) + bv.y, 0.f);
        const float r2 = fmaxf(__low2float(c2[2][tt]) + __high2float(c2[2][tt]) + bv.z, 0.f);
        const float r3 = fmaxf(__low2float(c2[3][tt]) + __high2float(c2[3][tt]) + bv.w, 0.f);
        __half2 p01 = __floats2half2_rn(r0, r1);
        __half2 p23 = __floats2half2_rn(r2, r3);
        uint2 pk;
        pk.x = *(unsigned*)&p01;
        pk.y = *(unsigned*)&p23;
        *(uint2*)&sh16[U_FF + (t0+tt)*264 + f0] = pk;
      }
    }
    // FF -> FF2 is wave-local

    // ---- FF2 + b2 + residual(x1) -> LN2 -> +out -> LN3 (wave-local) ----
    {
      const unsigned short* w2p = w2t + lane*8;
      __half2 cA[3], cB[3];
#pragma unroll
      for (int tt = 0; tt < 3; ++tt) { cA[tt] = hz; cB[tt] = hz; }
#pragma unroll 1
      for (int kp = 0; kp < 16; ++kp) {
        {
          const int kb = 2*kp;
          const uint4 w4 = *(const uint4*)(w2p + kb*512);
          const __half2* w2_ = (const __half2*)&w4;
#pragma unroll
          for (int tt = 0; tt < 3; ++tt) {
            const uint4 a4 = *(const uint4*)&sh16[U_FF + (t0+tt)*264 + 8*kb];
            const __half2* a2 = (const __half2*)&a4;
#pragma unroll
            for (int j = 0; j < 4; ++j) cA[tt] = __hfma2(a2[j], w2_[j], cA[tt]);
          }
        }
        {
          const int kb = 2*kp + 1;
          const uint4 w4 = *(const uint4*)(w2p + kb*512);
          const __half2* w2_ = (const __half2*)&w4;
#pragma unroll
          for (int tt = 0; tt < 3; ++tt) {
            const uint4 a4 = *(const uint4*)&sh16[U_FF + (t0+tt)*264 + 8*kb];
            const __half2* a2 = (const __half2*)&a4;
#pragma unroll
            for (int j = 0; j < 4; ++j) cB[tt] = __hfma2(a2[j], w2_[j], cB[tt]);
          }
        }
      }
#pragma unroll
      for (int tt = 0; tt < 3; ++tt) {
        float v = __low2float(cA[tt]) + __high2float(cA[tt])
                + __low2float(cB[tt]) + __high2float(cB[tt])
                + ff_b2[l*EE + lane] + x1v[tt];
        float mu = wave_sum(v) * (1.f/64);
        float dd = v - mu;
        float var = wave_sum(dd*dd) * (1.f/64);
        const float blk = dd * rsqrtf(var + 1e-5f) * ln2_g[l*EE + lane] + ln2_b[l*EE + lane];
        float w = blk + outv[tt];
        mu = wave_sum(w) * (1.f/64);
        dd = w - mu;
        var = wave_sum(dd*dd) * (1.f/64);
        outv[tt] = dd * rsqrtf(var + 1e-5f) * lng[l*EE + lane] + lnb[l*EE + lane];
      }
    }
  }

  // stage final residual (f32) into F_FIN (aliases FF; cross-wave -> fence both sides)
  __syncthreads();
#pragma unroll
  for (int tt = 0; tt < 3; ++tt)
    lds[F_FIN + (t0+tt)*68 + lane] = outv[tt];
  __syncthreads();

  // final conv2 (time mix) + relu + conv3 (embed contraction)
  float xt[12];
#pragma unroll
  for (int t = 0; t < 12; ++t) xt[t] = lds[F_FIN + t*68 + lane];
  const float c3w = conv3_w[lane];
  for (int o = wid; o < 12; o += 4) {
    float a = conv2_b[o];
#pragma unroll
    for (int t = 0; t < 12; ++t) a += xt[t] * conv2_w[o*TT + t];
    a = fmaxf(a, 0.f);
    const float s = wave_sum(a * c3w);
    if (lane == 0) fout[bn*TT + o] = s + conv3_b[0];
  }
}

// ---------------------------------------------------------------------------
extern "C" void kernel_launch(void* const* d_in, const int* in_sizes, int n_in,
                              void* d_out, int out_size, void* d_ws, size_t ws_size,
                              hipStream_t stream) {
  const float* x       = (const float*)d_in[0];
  const int*   adj     = (const int*)  d_in[1];
  const float* gat_W2  = (const float*)d_in[2];
  const float* gat_a   = (const float*)d_in[3];
  const float* gat_b   = (const float*)d_in[4];
  const float* conv1_w = (const float*)d_in[5];
  const float* conv1_b = (const float*)d_in[6];
  const float* temb    = (const float*)d_in[7];
  const float* Wq      = (const float*)d_in[8];
  const float* Wk      = (const float*)d_in[9];
  const float* Wv      = (const float*)d_in[10];
  const float* Wo      = (const float*)d_in[11];
  const float* bo      = (const float*)d_in[12];
  const float* ln1_g   = (const float*)d_in[13];
  const float* ln1_b   = (const float*)d_in[14];
  const float* ln2_g   = (const float*)d_in[15];
  const float* ln2_b   = (const float*)d_in[16];
  const float* ff_w1   = (const float*)d_in[17];
  const float* ff_b1   = (const float*)d_in[18];
  const float* ff_w2   = (const float*)d_in[19];
  const float* ff_b2   = (const float*)d_in[20];
  const float* lng     = (const float*)d_in[21];
  const float* lnb     = (const float*)d_in[22];
  const float* conv2_w = (const float*)d_in[23];
  const float* conv2_b = (const float*)d_in[24];
  const float* conv3_w = (const float*)d_in[25];
  const float* conv3_b = (const float*)d_in[26];

  unsigned short* wb   = (unsigned short*)d_ws;          // 98304 u16 (f16)
  unsigned short* out0 = wb + 98304;                     // 8*207*768 u16 (f16)
  float* fout = (float*)d_out;

  prep_weights<<<384, 256, 0, stream>>>(Wq, Wk, Wv, Wo, ff_w1, ff_w2, wb);

  gat_conv1_kernel<<<BB*NN, 256, 0, stream>>>(
      x, adj, gat_W2, gat_a, gat_b, conv1_w, conv1_b, out0);

  xf_final_kernel<<<BB*NN, 256, 0, stream>>>(
      out0, wb, temb, bo, ln1_g, ln1_b, ln2_g, ln2_b,
      ff_b1, ff_b2, lng, lnb, conv2_w, conv2_b, conv3_w, conv3_b, fout);
}

// Round 13
// 229.256 us; speedup vs baseline: 1.5322x; 1.0293x over previous
//
#include <hip/hip_runtime.h>
#include <hip/hip_bf16.h>
#include <hip/hip_fp16.h>

#define NN   207
#define BB   8
#define TT   12
#define EE   64
#define FFD  256
#define NGH  8
#define GALPHA 0.2f
#define GNEG  -9e15f

// ---- Kernel B LDS layout ----
// u16-unit offsets (all ≡0 mod 8 → 16B aligned)
#define U_QQ  0       // f16 [12][72]
#define U_X1  864     // f16 [12][72]
#define U_QB  1728    // f16 [12][72]
#define U_KB  2592
#define U_VB  3456
#define F_SC  2160    // f32 units (byte 8640): f32 [4][144]
#define U_CTX 5472    // f16 [12][72]
#define U_FF  6336    // f16 [12][264]
#define F_FIN 3168    // f32 units (byte 12672), aliases U_FF (dead at final)
#define LDS_F32 4752  // 19008 B

__device__ __forceinline__ float lo_f(unsigned u) { return __uint_as_float(u << 16); }
__device__ __forceinline__ float hi_f(unsigned u) { return __uint_as_float(u & 0xffff0000u); }
__device__ __forceinline__ unsigned pk2(float a, float b) {
  unsigned la = (unsigned)__bfloat16_as_ushort(__float2bfloat16(a));
  unsigned lb = (unsigned)__bfloat16_as_ushort(__float2bfloat16(b));
  return la | (lb << 16);
}
__device__ __forceinline__ unsigned short h16u(float a) {
  return __half_as_ushort(__float2half(a));
}
__device__ __forceinline__ float u16f(unsigned short s) {
  return __half2float(__ushort_as_half(s));
}
__device__ __forceinline__ float tanh_fast(float x) {
  return 1.f - 2.f * __builtin_amdgcn_rcpf(__expf(2.f * x) + 1.f);
}

// ---- DPP wave reduction, rocPRIM pattern ----
// 4x row_ror (verified HW r8/r10) -> every lane holds its 16-lane row sum;
// row_bcast15 (mask 0xa): row1+=r0, row3+=r2; row_bcast31 (mask 0xc):
// rows2,3 += (r0+r1) -> lanes 48-63 hold the full sum; readlane(63).
__device__ __forceinline__ float wave_sum(float v) {
  v += __int_as_float(__builtin_amdgcn_update_dpp(0, __float_as_int(v), 0x121, 0xf, 0xf, false));
  v += __int_as_float(__builtin_amdgcn_update_dpp(0, __float_as_int(v), 0x122, 0xf, 0xf, false));
  v += __int_as_float(__builtin_amdgcn_update_dpp(0, __float_as_int(v), 0x124, 0xf, 0xf, false));
  v += __int_as_float(__builtin_amdgcn_update_dpp(0, __float_as_int(v), 0x128, 0xf, 0xf, false));
  v += __int_as_float(__builtin_amdgcn_update_dpp(0, __float_as_int(v), 0x142, 0xa, 0xf, false));
  v += __int_as_float(__builtin_amdgcn_update_dpp(0, __float_as_int(v), 0x143, 0xc, 0xf, false));
  return __int_as_float(__builtin_amdgcn_readlane(__float_as_int(v), 63));
}

// ===========================================================================
// Workspace (u16 from d_ws): wb[98304] f16 weights, then out0 f16[8*207*768].
// Total 2.74 MB < 5.09 MB proven watermark.
// ===========================================================================

// ===========================================================================
// Prep: f16 transposed+kb-tiled weights (round-7 layout, f16 payload).
// (u16 idx): QT/KT/VT/OT: which*8192 + l*4096 + kb*512 + c*8 + j  (k=8kb+j)
//   W1T: 32768 + l*16384 + kb*2048 + f*8 + j      (kb 0..7)
//   W2T: 65536 + l*16384 + kb*512  + e*8 + j      (kb 0..31)
// ===========================================================================
__global__ __launch_bounds__(256) void prep_weights(
    const float* __restrict__ Wq, const float* __restrict__ Wk,
    const float* __restrict__ Wv, const float* __restrict__ Wo,
    const float* __restrict__ ff_w1, const float* __restrict__ ff_w2,
    unsigned short* __restrict__ wb)
{
  const int idx = blockIdx.x * 256 + threadIdx.x;   // < 98304
  float v;
  if (idx < 32768) {
    const int which = idx >> 13;
    const int r = idx & 8191;
    const int l = r >> 12, q = r & 4095;
    const int kb = q >> 9, c = (q >> 3) & 63, j = q & 7;
    const float* W = (which == 0) ? Wq : (which == 1) ? Wk : (which == 2) ? Wv : Wo;
    v = W[l*4096 + (8*kb + j)*64 + c];
  } else if (idx < 65536) {
    const int r = idx - 32768;
    const int l = r >> 14, q = r & 16383;
    const int kb = q >> 11, f = (q >> 3) & 255, j = q & 7;
    v = ff_w1[l*16384 + (8*kb + j)*256 + f];
  } else {
    const int r = idx - 65536;
    const int l = r >> 14, q = r & 16383;
    const int kb = q >> 9, e = (q >> 3) & 63, j = q & 7;
    v = ff_w2[l*16384 + (8*kb + j)*64 + e];
  }
  wb[idx] = h16u(v);
}

// ===========================================================================
// Kernel A: GAT (8 heads) + conv1 (round-10 structure + fast wave_sum).
// ===========================================================================
#define A_GW 2484   // u32 xs_pk[12][207] then 96 floats of GAT params

__global__ __launch_bounds__(256) void gat_conv1_kernel(
    const float* __restrict__ x,        const int* __restrict__ adj,
    const float* __restrict__ gat_W2,   const float* __restrict__ gat_a,
    const float* __restrict__ gat_b,    const float* __restrict__ conv1_w,
    const float* __restrict__ conv1_b,  unsigned short* __restrict__ out0)
{
  __shared__ float lds[A_GW + 96];
  unsigned* au = (unsigned*)lds;

  const int bn   = blockIdx.x;
  const int b    = bn / NN;
  const int i    = bn % NN;
  const int tid  = threadIdx.x;
  const int lane = tid & 63;
  const int wid  = tid >> 6;

  const float* xb = x + b * 2 * NN * TT;
  for (int idx = tid; idx < NN * TT; idx += 256) {
    const int n = idx / TT, t = idx % TT;
    au[t * NN + n] = pk2(xb[idx], xb[NN * TT + idx]);
  }
  if (tid < 64) lds[A_GW + tid] = gat_W2[tid];
  if (tid < 16) { lds[A_GW + 64 + tid] = gat_a[tid]; lds[A_GW + 80 + tid] = gat_b[tid]; }
  __syncthreads();

  float aokf[4];
  int   row0[4], row1[4];
  {
    const int NSQ = NN * NN;
#pragma unroll
    for (int q = 0; q < 4; ++q) {
      const int j = lane + 64 * q;
      const int jj = (j < NN) ? j : 0;
      const int r0 = 2 * (i * NN + jj), r1 = r0 + 1;
      row0[q] = (r0 < NSQ) ? (r0 / NN) : ((r0 - NSQ) % NN);
      row1[q] = (r1 < NSQ) ? (r1 / NN) : ((r1 - NSQ) % NN);
      aokf[q] = ((j < NN) && adj[(b * NN + i) * NN + jj] > 0) ? 1.f : 0.f;
    }
  }

  float xr00[3][4], xr01[3][4], xr10[3][4], xr11[3][4], xj0[3][4], xj1[3][4];
#pragma unroll
  for (int tk = 0; tk < 3; ++tk) {
    const unsigned* xst = au + (wid + 4 * tk) * NN;
#pragma unroll
    for (int q = 0; q < 4; ++q) {
      int j = lane + 64 * q; if (j >= NN) j = 0;
      const unsigned u0 = xst[row0[q]], u1 = xst[row1[q]], uj = xst[j];
      xr00[tk][q] = lo_f(u0); xr01[tk][q] = hi_f(u0);
      xr10[tk][q] = lo_f(u1); xr11[tk][q] = hi_f(u1);
      xj0[tk][q]  = lo_f(uj); xj1[tk][q]  = hi_f(uj);
    }
  }

  float acc0[3] = {0.f, 0.f, 0.f}, acc1[3] = {0.f, 0.f, 0.f};
#pragma unroll 1
  for (int h = 0; h < NGH; ++h) {
    const float w0 = lds[A_GW + h*8 + 0], w1_ = lds[A_GW + h*8 + 1];
    const float w2_= lds[A_GW + h*8 + 2], w3  = lds[A_GW + h*8 + 3];
    const float w4 = lds[A_GW + h*8 + 4], w5  = lds[A_GW + h*8 + 5];
    const float w6 = lds[A_GW + h*8 + 6], w7  = lds[A_GW + h*8 + 7];
    const float a0 = lds[A_GW + 64 + h*2], a1 = lds[A_GW + 64 + h*2 + 1];
    const float gb0 = lds[A_GW + 80 + h*2], gb1 = lds[A_GW + 80 + h*2 + 1];
    float s0[3] = {0.f,0.f,0.f}, s1[3] = {0.f,0.f,0.f}, s2[3] = {0.f,0.f,0.f};
#pragma unroll
    for (int tk = 0; tk < 3; ++tk) {
#pragma unroll
      for (int q = 0; q < 4; ++q) {
        float wx0 = xr00[tk][q]*w0 + xr01[tk][q]*w2_ + xr10[tk][q]*w4 + xr11[tk][q]*w6;
        float wx1 = xr00[tk][q]*w1_ + xr01[tk][q]*w3 + xr10[tk][q]*w5 + xr11[tk][q]*w7;
        wx0 = (wx0 > 0.f) ? wx0 : GALPHA * wx0;
        wx1 = (wx1 > 0.f) ? wx1 : GALPHA * wx1;
        float e = a0 * wx0 + a1 * wx1;
        e = (aokf[q] > 0.f) ? e : GNEG;       // exp(GNEG) underflows to exactly 0
        const float ex = __expf(e);
        s0[tk] += ex; s1[tk] += ex * xj0[tk][q]; s2[tk] += ex * xj1[tk][q];
      }
    }
#pragma unroll
    for (int tk = 0; tk < 3; ++tk) {
      const float d0 = wave_sum(s0[tk]);
      const float d1 = wave_sum(s1[tk]);
      const float d2 = wave_sum(s2[tk]);
      const float inv = __builtin_amdgcn_rcpf(d0);
      acc0[tk] += tanh_fast(d1 * inv + gb0);
      acc1[tk] += tanh_fast(d2 * inv + gb1);
    }
  }

  {
    const float c1w0 = conv1_w[lane],       c1w1 = conv1_w[64 + lane];
    const float c1w2 = conv1_w[128 + lane], c1w3 = conv1_w[192 + lane];
    const float c1b  = conv1_b[lane];
#pragma unroll
    for (int tk = 0; tk < 3; ++tk) {
      const int t = wid + 4 * tk;
      const unsigned up = au[t * NN + i];
      const float g0 = acc0[tk] * (1.f / NGH), g1 = acc1[tk] * (1.f / NGH);
      out0[bn*768 + t*EE + lane] =
          h16u(lo_f(up)*c1w0 + hi_f(up)*c1w1 + g0*c1w2 + g1*c1w3 + c1b);
    }
  }
}

// ===========================================================================
// Kernel B: 2-layer transformer + final convs. f16 data plane, __hfma2,
// one-pass (E[x^2]-mu^2) LayerNorms with independent wave_sums.
// ===========================================================================
__global__ __launch_bounds__(256) void xf_final_kernel(
    const unsigned short* __restrict__ out0,  // f16 (B,N,T,E)
    const unsigned short* __restrict__ wb,    // f16 transposed weights
    const float* __restrict__ temb,
    const float* __restrict__ bo,
    const float* __restrict__ ln1_g, const float* __restrict__ ln1_b,
    const float* __restrict__ ln2_g, const float* __restrict__ ln2_b,
    const float* __restrict__ ff_b1, const float* __restrict__ ff_b2,
    const float* __restrict__ lng, const float* __restrict__ lnb,
    const float* __restrict__ conv2_w, const float* __restrict__ conv2_b,
    const float* __restrict__ conv3_w, const float* __restrict__ conv3_b,
    float* __restrict__ fout)
{
  __shared__ float lds[LDS_F32];
  unsigned*       au   = (unsigned*)lds;
  unsigned short* sh16 = (unsigned short*)lds;

  const int bn   = blockIdx.x;
  const int tid  = threadIdx.x;
  const int lane = tid & 63;
  const int wid  = tid >> 6;
  const int t0   = 3 * wid;

  const __half2 hz = __floats2half2_rn(0.f, 0.f);

  float outv[3];
#pragma unroll
  for (int tt = 0; tt < 3; ++tt)
    outv[tt] = u16f(out0[bn*768 + (t0 + tt)*EE + lane]);

  for (int l = 0; l < 2; ++l) {
    const unsigned short* wqt = wb + l*4096;
    const unsigned short* wkt = wb + 8192  + l*4096;
    const unsigned short* wvt = wb + 16384 + l*4096;
    const unsigned short* wot = wb + 24576 + l*4096;
    const unsigned short* w1t = wb + 32768 + l*16384;
    const unsigned short* w2t = wb + 65536 + l*16384;

    // qq = out + temb (regs + f16 LDS for same-wave QKV broadcast reads)
    float qqv[3];
#pragma unroll
    for (int tt = 0; tt < 3; ++tt) {
      qqv[tt] = outv[tt] + temb[(t0 + tt)*EE + lane];
      sh16[U_QQ + (t0 + tt)*72 + lane] = h16u(qqv[tt]);
    }

    // ---- QKV: lane owns col, wave owns t-triple (wave-local) ----
    {
      const unsigned short* wqp = wqt + lane*8;
      const unsigned short* wkp = wkt + lane*8;
      const unsigned short* wvp = wvt + lane*8;
      __half2 cq[3], ck[3], cv[3];
#pragma unroll
      for (int tt = 0; tt < 3; ++tt) { cq[tt] = hz; ck[tt] = hz; cv[tt] = hz; }
#pragma unroll 1
      for (int kb = 0; kb < 8; ++kb) {
        const uint4 wq4 = *(const uint4*)(wqp + kb*512);
        const uint4 wk4 = *(const uint4*)(wkp + kb*512);
        const uint4 wv4 = *(const uint4*)(wvp + kb*512);
        uint4 a4[3];
#pragma unroll
        for (int tt = 0; tt < 3; ++tt)
          a4[tt] = *(const uint4*)&sh16[U_QQ + (t0+tt)*72 + 8*kb];
        const __half2* wq2 = (const __half2*)&wq4;
        const __half2* wk2 = (const __half2*)&wk4;
        const __half2* wv2 = (const __half2*)&wv4;
#pragma unroll
        for (int tt = 0; tt < 3; ++tt) {
          const __half2* a2 = (const __half2*)&a4[tt];
#pragma unroll
          for (int j = 0; j < 4; ++j) {
            cq[tt] = __hfma2(a2[j], wq2[j], cq[tt]);
            ck[tt] = __hfma2(a2[j], wk2[j], ck[tt]);
            cv[tt] = __hfma2(a2[j], wv2[j], cv[tt]);
          }
        }
      }
#pragma unroll
      for (int tt = 0; tt < 3; ++tt) {
        const int t = t0 + tt;
        sh16[U_QB + t*72 + lane] = h16u(__low2float(cq[tt]) + __high2float(cq[tt]));
        sh16[U_KB + t*72 + lane] = h16u(__low2float(ck[tt]) + __high2float(ck[tt]));
        sh16[U_VB + t*72 + lane] = h16u(__low2float(cv[tt]) + __high2float(cv[tt]));
      }
    }
    __syncthreads();   // bar B: QKV visible to all waves

    // ---- Attention: wave h owns head h (wave-local) ----
    {
      const int h = wid;
      if (lane < 48) {
        const int t = lane >> 2, s0 = 3*(lane & 3);
        const uint4 qa = *(const uint4*)&sh16[U_QB + t*72 + h*16];
        const uint4 qb = *(const uint4*)&sh16[U_QB + t*72 + h*16 + 8];
        const __half2* q2a = (const __half2*)&qa;
        const __half2* q2b = (const __half2*)&qb;
#pragma unroll
        for (int ss = 0; ss < 3; ++ss) {
          const int s = s0 + ss;
          const uint4 ka = *(const uint4*)&sh16[U_KB + s*72 + h*16];
          const uint4 kc = *(const uint4*)&sh16[U_KB + s*72 + h*16 + 8];
          const __half2* k2a = (const __half2*)&ka;
          const __half2* k2b = (const __half2*)&kc;
          __half2 d2 = hz;
#pragma unroll
          for (int j = 0; j < 4; ++j) {
            d2 = __hfma2(q2a[j], k2a[j], d2);
            d2 = __hfma2(q2b[j], k2b[j], d2);
          }
          lds[F_SC + h*144 + t*12 + s] = (__low2float(d2) + __high2float(d2)) * 0.25f;
        }
      }
      __builtin_amdgcn_wave_barrier();
      if (lane < 12) {
        float* row = &lds[F_SC + h*144 + lane*12];
        float m = row[0];
#pragma unroll
        for (int s = 1; s < 12; ++s) m = fmaxf(m, row[s]);
        float ex[12]; float sum = 0.f;
#pragma unroll
        for (int s = 0; s < 12; ++s) { ex[s] = __expf(row[s] - m); sum += ex[s]; }
        const float inv = __builtin_amdgcn_rcpf(sum);
#pragma unroll
        for (int s = 0; s < 12; ++s) row[s] = ex[s] * inv;
      }
      __builtin_amdgcn_wave_barrier();
      {
        const int d = lane & 15, tq = lane >> 4;
#pragma unroll
        for (int tt = 0; tt < 3; ++tt) {
          const int t = tq + 4*tt;
          float cacc = 0.f;
#pragma unroll
          for (int s = 0; s < 12; ++s) {
            const float p = lds[F_SC + h*144 + t*12 + s];
            const unsigned uv = au[(U_VB/2) + s*36 + h*8 + (d >> 1)];
            const __half2 hv = *(const __half2*)&uv;
            cacc += p * ((d & 1) ? __high2float(hv) : __low2float(hv));
          }
          sh16[U_CTX + t*72 + h*16 + d] = h16u(cacc);
        }
      }
    }
    __syncthreads();   // bar C: ctx visible to all waves

    // ---- Wo + bias + residual(qq) -> LN1 (one-pass) -> X1 (f16) ----
    float x1v[3];
    {
      const unsigned short* wop = wot + lane*8;
      __half2 co[3];
#pragma unroll
      for (int tt = 0; tt < 3; ++tt) co[tt] = hz;
#pragma unroll 1
      for (int kb = 0; kb < 8; ++kb) {
        const uint4 w4 = *(const uint4*)(wop + kb*512);
        const __half2* w2_ = (const __half2*)&w4;
        uint4 a4[3];
#pragma unroll
        for (int tt = 0; tt < 3; ++tt)
          a4[tt] = *(const uint4*)&sh16[U_CTX + (t0+tt)*72 + 8*kb];
#pragma unroll
        for (int tt = 0; tt < 3; ++tt) {
          const __half2* a2 = (const __half2*)&a4[tt];
#pragma unroll
          for (int j = 0; j < 4; ++j) co[tt] = __hfma2(a2[j], w2_[j], co[tt]);
        }
      }
#pragma unroll
      for (int tt = 0; tt < 3; ++tt) {
        float v = __low2float(co[tt]) + __high2float(co[tt]) + bo[l*EE + lane] + qqv[tt];
        const float sA = wave_sum(v);
        const float sB = wave_sum(v*v);
        const float mu = sA * (1.f/64);
        const float var = sB * (1.f/64) - mu*mu;
        x1v[tt] = (v - mu) * rsqrtf(var + 1e-5f) * ln1_g[l*EE + lane] + ln1_b[l*EE + lane];
        sh16[U_X1 + (t0+tt)*72 + lane] = h16u(x1v[tt]);
      }
    }
    // X1 -> FF1 is wave-local (same wave wrote its rows)

    // ---- FF1 + relu -> FF (f16): lane owns f-quad, wave owns t-triple ----
    {
      const int f0 = 4*lane;
      __half2 c2[4][3];
#pragma unroll
      for (int ff = 0; ff < 4; ++ff)
#pragma unroll
        for (int tt = 0; tt < 3; ++tt) c2[ff][tt] = hz;
#pragma unroll 1
      for (int kb = 0; kb < 8; ++kb) {
        uint4 w4[4];
#pragma unroll
        for (int ff = 0; ff < 4; ++ff)
          w4[ff] = *(const uint4*)(w1t + kb*2048 + (f0+ff)*8);
        uint4 a4[3];
#pragma unroll
        for (int tt = 0; tt < 3; ++tt)
          a4[tt] = *(const uint4*)&sh16[U_X1 + (t0+tt)*72 + 8*kb];
#pragma unroll
        for (int ff = 0; ff < 4; ++ff) {
          const __half2* w2_ = (const __half2*)&w4[ff];
#pragma unroll
          for (int tt = 0; tt < 3; ++tt) {
            const __half2* a2 = (const __half2*)&a4[tt];
#pragma unroll
            for (int j = 0; j < 4; ++j) c2[ff][tt] = __hfma2(a2[j], w2_[j], c2[ff][tt]);
          }
        }
      }
      const float4 bv = *(const float4*)&ff_b1[l*FFD + f0];
#pragma unroll
      for (int tt = 0; tt < 3; ++tt) {
        const float r0 = fmaxf(__low2float(c2[0][tt]) + __high2float(c2[0][tt]) + bv.x, 0.f);
        const float r1 = fmaxf(__low2float(c2[1][tt]) + __high2float(c2[1][tt]) + bv.y, 0.f);
        const float r2 = fmaxf(__low2float(c2[2][tt]) + __high2float(c2[2][tt]) + bv.z, 0.f);
        const float r3 = fmaxf(__low2float(c2[3][tt]) + __high2float(c2[3][tt]) + bv.w, 0.f);
        __half2 p01 = __floats2half2_rn(r0, r1);
        __half2 p23 = __floats2half2_rn(r2, r3);
        uint2 pk;
        pk.x = *(unsigned*)&p01;
        pk.y = *(unsigned*)&p23;
        *(uint2*)&sh16[U_FF + (t0+tt)*264 + f0] = pk;
      }
    }
    // FF -> FF2 is wave-local

    // ---- FF2 + b2 + residual(x1) -> LN2 -> +out -> LN3 (one-pass LNs) ----
    {
      const unsigned short* w2p = w2t + lane*8;
      __half2 cA[3], cB[3];
#pragma unroll
      for (int tt = 0; tt < 3; ++tt) { cA[tt] = hz; cB[tt] = hz; }
#pragma unroll 1
      for (int kp = 0; kp < 16; ++kp) {
        {
          const int kb = 2*kp;
          const uint4 w4 = *(const uint4*)(w2p + kb*512);
          const __half2* w2_ = (const __half2*)&w4;
#pragma unroll
          for (int tt = 0; tt < 3; ++tt) {
            const uint4 a4 = *(const uint4*)&sh16[U_FF + (t0+tt)*264 + 8*kb];
            const __half2* a2 = (const __half2*)&a4;
#pragma unroll
            for (int j = 0; j < 4; ++j) cA[tt] = __hfma2(a2[j], w2_[j], cA[tt]);
          }
        }
        {
          const int kb = 2*kp + 1;
          const uint4 w4 = *(const uint4*)(w2p + kb*512);
          const __half2* w2_ = (const __half2*)&w4;
#pragma unroll
          for (int tt = 0; tt < 3; ++tt) {
            const uint4 a4 = *(const uint4*)&sh16[U_FF + (t0+tt)*264 + 8*kb];
            const __half2* a2 = (const __half2*)&a4;
#pragma unroll
            for (int j = 0; j < 4; ++j) cB[tt] = __hfma2(a2[j], w2_[j], cB[tt]);
          }
        }
      }
#pragma unroll
      for (int tt = 0; tt < 3; ++tt) {
        float v = __low2float(cA[tt]) + __high2float(cA[tt])
                + __low2float(cB[tt]) + __high2float(cB[tt])
                + ff_b2[l*EE + lane] + x1v[tt];
        const float sA = wave_sum(v);
        const float sB = wave_sum(v*v);
        float mu = sA * (1.f/64);
        float var = sB * (1.f/64) - mu*mu;
        const float blk = (v - mu) * rsqrtf(var + 1e-5f) * ln2_g[l*EE + lane] + ln2_b[l*EE + lane];
        float w = blk + outv[tt];
        const float sC = wave_sum(w);
        const float sD = wave_sum(w*w);
        mu = sC * (1.f/64);
        var = sD * (1.f/64) - mu*mu;
        outv[tt] = (w - mu) * rsqrtf(var + 1e-5f) * lng[l*EE + lane] + lnb[l*EE + lane];
      }
    }
  }

  // stage final residual (f32) into F_FIN (aliases FF; fence both sides)
  __syncthreads();
#pragma unroll
  for (int tt = 0; tt < 3; ++tt)
    lds[F_FIN + (t0+tt)*68 + lane] = outv[tt];
  __syncthreads();

  // final conv2 (time mix) + relu + conv3 (embed contraction)
  float xt[12];
#pragma unroll
  for (int t = 0; t < 12; ++t) xt[t] = lds[F_FIN + t*68 + lane];
  const float c3w = conv3_w[lane];
  for (int o = wid; o < 12; o += 4) {
    float a = conv2_b[o];
#pragma unroll
    for (int t = 0; t < 12; ++t) a += xt[t] * conv2_w[o*TT + t];
    a = fmaxf(a, 0.f);
    const float s = wave_sum(a * c3w);
    if (lane == 0) fout[bn*TT + o] = s + conv3_b[0];
  }
}

// ---------------------------------------------------------------------------
extern "C" void kernel_launch(void* const* d_in, const int* in_sizes, int n_in,
                              void* d_out, int out_size, void* d_ws, size_t ws_size,
                              hipStream_t stream) {
  const float* x       = (const float*)d_in[0];
  const int*   adj     = (const int*)  d_in[1];
  const float* gat_W2  = (const float*)d_in[2];
  const float* gat_a   = (const float*)d_in[3];
  const float* gat_b   = (const float*)d_in[4];
  const float* conv1_w = (const float*)d_in[5];
  const float* conv1_b = (const float*)d_in[6];
  const float* temb    = (const float*)d_in[7];
  const float* Wq      = (const float*)d_in[8];
  const float* Wk      = (const float*)d_in[9];
  const float* Wv      = (const float*)d_in[10];
  const float* Wo      = (const float*)d_in[11];
  const float* bo      = (const float*)d_in[12];
  const float* ln1_g   = (const float*)d_in[13];
  const float* ln1_b   = (const float*)d_in[14];
  const float* ln2_g   = (const float*)d_in[15];
  const float* ln2_b   = (const float*)d_in[16];
  const float* ff_w1   = (const float*)d_in[17];
  const float* ff_b1   = (const float*)d_in[18];
  const float* ff_w2   = (const float*)d_in[19];
  const float* ff_b2   = (const float*)d_in[20];
  const float* lng     = (const float*)d_in[21];
  const float* lnb     = (const float*)d_in[22];
  const float* conv2_w = (const float*)d_in[23];
  const float* conv2_b = (const float*)d_in[24];
  const float* conv3_w = (const float*)d_in[25];
  const float* conv3_b = (const float*)d_in[26];

  unsigned short* wb   = (unsigned short*)d_ws;          // 98304 u16 (f16)
  unsigned short* out0 = wb + 98304;                     // 8*207*768 u16 (f16)
  float* fout = (float*)d_out;

  prep_weights<<<384, 256, 0, stream>>>(Wq, Wk, Wv, Wo, ff_w1, ff_w2, wb);

  gat_conv1_kernel<<<BB*NN, 256, 0, stream>>>(
      x, adj, gat_W2, gat_a, gat_b, conv1_w, conv1_b, out0);

  xf_final_kernel<<<BB*NN, 256, 0, stream>>>(
      out0, wb, temb, bo, ln1_g, ln1_b, ln2_g, ln2_b,
      ff_b1, ff_b2, lng, lnb, conv2_w, conv2_b, conv3_w, conv3_b, fout);
}